// Round 1
// baseline (1240.797 us; speedup 1.0000x reference)
//
#include <hip/hip_runtime.h>
#include <stdint.h>
#include <math.h>

// ---------------------------------------------------------------------------
// SemanticAwareQuerySampler — fp32 correctness-first implementation.
//
// RNG_SCHEME selects how jax.random's threefry bits are generated:
//   0: partitionable (default in JAX >= 0.4.30): bits(f) = o0^o1 of
//      threefry2x32(key, [hi32(f), lo32(f)])
//   1: partitionable, word0 only
//   2: legacy (threefry_partitionable=False): split-halves counter scheme
//   3: partitionable, word1 only
#define RNG_SCHEME 0

#define NB 16
#define HD_ 80
#define WD_ 80
#define HWD 6400
#define MAXQ 800
#define EMB 256
#define NMEM 8400
#define BQ (NB*MAXQ)          // 12800
#define HALF_ORIG 40960000ull // (16*800*6400)/2

__device__ __forceinline__ void tf2x32(uint32_t x0, uint32_t x1,
                                       uint32_t& o0, uint32_t& o1) {
  const uint32_t ks0 = 0u;
  const uint32_t ks1 = 42u;
  const uint32_t ks2 = 0x1BD11BDAu ^ 0u ^ 42u;
  x0 += ks0; x1 += ks1;
#define TF_ROT(r) { x0 += x1; x1 = (x1 << (r)) | (x1 >> (32 - (r))); x1 ^= x0; }
  TF_ROT(13) TF_ROT(15) TF_ROT(26) TF_ROT(6)
  x0 += ks1; x1 += ks2 + 1u;
  TF_ROT(17) TF_ROT(29) TF_ROT(16) TF_ROT(24)
  x0 += ks2; x1 += ks0 + 2u;
  TF_ROT(13) TF_ROT(15) TF_ROT(26) TF_ROT(6)
  x0 += ks0; x1 += ks1 + 3u;
  TF_ROT(17) TF_ROT(29) TF_ROT(16) TF_ROT(24)
  x0 += ks1; x1 += ks2 + 4u;
  TF_ROT(13) TF_ROT(15) TF_ROT(26) TF_ROT(6)
  x0 += ks2; x1 += ks0 + 5u;
#undef TF_ROT
  o0 = x0; o1 = x1;
}

__device__ __forceinline__ uint32_t rng_bits(uint64_t f) {
#if RNG_SCHEME == 2
  uint32_t x0, x1, o0, o1;
  bool lo = f < HALF_ORIG;
  if (lo) { x0 = (uint32_t)f; x1 = (uint32_t)(f + HALF_ORIG); }
  else    { x0 = (uint32_t)(f - HALF_ORIG); x1 = (uint32_t)f; }
  tf2x32(x0, x1, o0, o1);
  return lo ? o0 : o1;
#else
  uint32_t o0, o1;
  tf2x32((uint32_t)(f >> 32), (uint32_t)f, o0, o1);
#if RNG_SCHEME == 0
  return o0 ^ o1;
#elif RNG_SCHEME == 1
  return o0;
#else
  return o1;
#endif
#endif
}

// ---------------------------------------------------------------------------
// nq = clip(floor(count*2), 100, 800); also emit as float output
__global__ void nq_kernel(const float* __restrict__ pc, int* __restrict__ nq_i,
                          float* __restrict__ out_nq) {
  int t = threadIdx.x;
  if (t < NB) {
    float v = floorf(pc[t] * 2.0f);
    int n = (int)v;
    n = n < 100 ? 100 : (n > 800 ? 800 : n);
    nq_i[t] = n;
    out_nq[t] = (float)n;
  }
}

// ---------------------------------------------------------------------------
// Gumbel-max categorical sampling. One block per (b,q); argmax over 6400
// cells of gumbel(flat_idx) + density/0.1. First-occurrence tie-break.
__global__ __launch_bounds__(256)
void sample_kernel(const float* __restrict__ density, const int* __restrict__ nq_i,
                   float* __restrict__ positions, float* __restrict__ mask_out) {
  __shared__ float sv[256];
  __shared__ int   si[256];
  const int bq = blockIdx.x;
  const int b = bq / MAXQ;
  const int q = bq - b * MAXQ;
  const int t = threadIdx.x;
  const float* lg = density + (size_t)b * HWD;
  const uint64_t base = (uint64_t)bq * HWD;

  float best = -3.0e38f;
  int besti = HWD;
#pragma unroll 5
  for (int i = 0; i < 25; ++i) {
    int c = t + (i << 8);
    uint32_t bits = rng_bits(base + (uint64_t)c);
    uint32_t mant = (bits >> 9) | 0x3f800000u;
    float u = __uint_as_float(mant) - 1.0f;
    if (u == 0.0f) u = 1.17549435e-38f;  // finfo(f32).tiny
    float g = -logf(-logf(u));
    float val = g + lg[c] / 0.1f;
    if (val > best) { best = val; besti = c; }  // per-thread c ascending
  }
  sv[t] = best; si[t] = besti;
  __syncthreads();
  for (int s = 128; s > 0; s >>= 1) {
    if (t < s) {
      float v2 = sv[t + s]; int i2 = si[t + s];
      if (v2 > sv[t] || (v2 == sv[t] && i2 < si[t])) { sv[t] = v2; si[t] = i2; }
    }
    __syncthreads();
  }
  if (t == 0) {
    int idx = si[0];
    int n = nq_i[b];
    float px, py;
    if (q >= n) { px = 0.0f; py = 0.0f; }
    else {
      py = (float)(idx / WD_) / 80.0f;
      px = (float)(idx % WD_) / 80.0f;
    }
    positions[2 * bq]     = px;
    positions[2 * bq + 1] = py;
    mask_out[bq] = (q >= n) ? 1.0f : 0.0f;
  }
}

// ---------------------------------------------------------------------------
// query_pos = Linear(2,128) -> tanh-GELU -> Linear(128,256). 16 queries/block.
__device__ __forceinline__ float gelu_tanh(float x) {
  float x3 = x * x * x;
  float inner = 0.7978845608028654f * (x + 0.044715f * x3);
  float cdf = 0.5f * (1.0f + tanhf(inner));
  return x * cdf;
}

__global__ __launch_bounds__(256)
void posmlp_kernel(const float* __restrict__ positions,
                   const float* __restrict__ w1, const float* __restrict__ b1,
                   const float* __restrict__ w2, const float* __restrict__ b2,
                   float* __restrict__ qpos) {
  __shared__ float ppos[16][2];
  __shared__ float h_all[16 * 128];
  const int t = threadIdx.x;
  const size_t q0 = (size_t)blockIdx.x * 16;
  if (t < 32) ppos[t >> 1][t & 1] = positions[q0 * 2 + t];
  __syncthreads();
  for (int j = t; j < 2048; j += 256) {
    int qi = j >> 7, k = j & 127;
    float x = ppos[qi][0] * w1[k] + ppos[qi][1] * w1[128 + k] + b1[k];
    h_all[j] = gelu_tanh(x);
  }
  __syncthreads();
  float acc[16];
#pragma unroll
  for (int qi = 0; qi < 16; ++qi) acc[qi] = 0.0f;
  for (int k = 0; k < 128; ++k) {
    float wv = w2[k * 256 + t];
#pragma unroll
    for (int qi = 0; qi < 16; ++qi) acc[qi] += h_all[qi * 128 + k] * wv;
  }
  float bv = b2[t];
#pragma unroll
  for (int qi = 0; qi < 16; ++qi)
    qpos[(q0 + qi) * 256 + t] = acc[qi] + bv;
}

// ---------------------------------------------------------------------------
// grid_sample (bilinear, align_corners=False, zero pad) of encoder memory P3.
__device__ __forceinline__ float bil_corner(const float* __restrict__ fmb,
                                            int yy, int xx, int e) {
  if (yy < 0 || yy >= HD_ || xx < 0 || xx >= WD_) return 0.0f;
  return fmb[((size_t)(yy * WD_ + xx)) * EMB + e];
}

__global__ __launch_bounds__(256)
void bilinear_kernel(const float* __restrict__ mem,
                     const float* __restrict__ positions,
                     float* __restrict__ sampled) {
  const int bq = blockIdx.x;
  const int b = bq / MAXQ;
  const int e = threadIdx.x;
  float px = positions[2 * bq], py = positions[2 * bq + 1];
  float gx = px * 2.0f - 1.0f;
  float gy = py * 2.0f - 1.0f;
  float x = (gx + 1.0f) * 0.5f * 80.0f - 0.5f;
  float y = (gy + 1.0f) * 0.5f * 80.0f - 0.5f;
  float x0f = floorf(x), y0f = floorf(y);
  float wx1 = x - x0f, wx0 = 1.0f - wx1;
  float wy1 = y - y0f, wy0 = 1.0f - wy1;
  int x0 = (int)x0f, y0 = (int)y0f;
  int x1 = x0 + 1, y1 = y0 + 1;
  const float* fmb = mem + (size_t)b * NMEM * EMB;
  float acc;
  acc  = bil_corner(fmb, y0, x0, e) * (wy0 * wx0);
  acc += bil_corner(fmb, y0, x1, e) * (wy0 * wx1);
  acc += bil_corner(fmb, y1, x0, e) * (wy1 * wx0);
  acc += bil_corner(fmb, y1, x1, e) * (wy1 * wx1);
  sampled[(size_t)bq * EMB + e] = acc;
}

// ---------------------------------------------------------------------------
// agent_init = agent_features(4096,64) @ qinit_w(64,256) + qinit_b
__global__ __launch_bounds__(256)
void agent_init_kernel(const float* __restrict__ af, const float* __restrict__ qw,
                       const float* __restrict__ qb, float* __restrict__ out) {
  __shared__ float xs[32 * 64];
  const int t = threadIdx.x;
  const size_t r0 = (size_t)blockIdx.x * 32;
  for (int j = t; j < 32 * 64; j += 256) xs[j] = af[r0 * 64 + j];
  __syncthreads();
  float acc[32];
#pragma unroll
  for (int r = 0; r < 32; ++r) acc[r] = 0.0f;
  for (int k = 0; k < 64; ++k) {
    float wv = qw[k * 256 + t];
#pragma unroll
    for (int r = 0; r < 32; ++r) acc[r] += xs[r * 64 + k] * wv;
  }
  float bv = qb[t];
#pragma unroll
  for (int r = 0; r < 32; ++r)
    out[(r0 + r) * 256 + t] = acc[r] + bv;
}

// ---------------------------------------------------------------------------
// Generic out[r][e] = sum_k X[r][k]*W[e][k] + b[e] (+ add). W is (256,256)
// row-major (torch (out,in) layout). 16 rows per block, K=256. In-place
// X==out is safe: rows fully staged to LDS before any write.
__global__ __launch_bounds__(256)
void proj_kernel(const float* __restrict__ X, const float* __restrict__ W,
                 const float* __restrict__ bias, const float* __restrict__ add,
                 float* __restrict__ out) {
  __shared__ float xs[16 * 256];
  __shared__ float wb[256 * 33];
  const int t = threadIdx.x;
  const size_t r0 = (size_t)blockIdx.x * 16;
  for (int j = t; j < 16 * 256; j += 256) xs[j] = X[r0 * 256 + j];
  float acc[16];
#pragma unroll
  for (int r = 0; r < 16; ++r) acc[r] = 0.0f;
  for (int kt = 0; kt < 8; ++kt) {
    __syncthreads();
    for (int j = t; j < 256 * 32; j += 256) {
      int e = j >> 5, kk = j & 31;
      wb[e * 33 + kk] = W[e * 256 + kt * 32 + kk];
    }
    __syncthreads();
#pragma unroll
    for (int kk = 0; kk < 32; ++kk) {
      float wv = wb[t * 33 + kk];
#pragma unroll
      for (int r = 0; r < 16; ++r)
        acc[r] += xs[r * 256 + kt * 32 + kk] * wv;
    }
  }
  float bv = bias[t];
#pragma unroll
  for (int r = 0; r < 16; ++r) {
    size_t row = r0 + r;
    float v = acc[r] + bv;
    if (add) v += add[row * 256 + t];
    out[row * 256 + t] = v;
  }
}

// ---------------------------------------------------------------------------
// 8-head cross attention: Q (16,800,256) x K/V (16,256,256), head_dim 32.
// Block = (b, 16-query chunk). Per head: stage K^T [32][257] -> scores ->
// softmax -> p_all; restage V [256][32] (union buffer) -> PV -> out.
__global__ __launch_bounds__(256)
void attn_kernel(const float* __restrict__ Qm, const float* __restrict__ Km,
                 const float* __restrict__ Vm, float* __restrict__ O) {
  __shared__ float kv[32 * 257];      // union: K^T [d][a] s257 / V [a][d] s32
  __shared__ float p_all[16 * 256];
  __shared__ float q_sh[16 * 32];
  __shared__ float part[8 * 32];
  __shared__ float red[8];
  const int t = threadIdx.x;
  const int b = blockIdx.x / 50;
  const int q0 = (blockIdx.x % 50) * 16;
  const float* Qb = Qm + ((size_t)b * MAXQ + q0) * 256;
  const float* Kb = Km + (size_t)b * 256 * 256;
  const float* Vb = Vm + (size_t)b * 256 * 256;
  const float SQRT_HD = 5.656854249492380195f;

  for (int h = 0; h < 8; ++h) {
    const int hoff = h * 32;
    for (int j = t; j < 512; j += 256) {
      int qi = j >> 5, d = j & 31;
      q_sh[j] = Qb[qi * 256 + hoff + d];
    }
    for (int j = t; j < 8192; j += 256) {
      int a = j >> 5, d = j & 31;
      kv[d * 257 + a] = Kb[a * 256 + hoff + d];
    }
    __syncthreads();
    for (int qi = 0; qi < 16; ++qi) {
      float s = 0.0f;
#pragma unroll
      for (int d = 0; d < 32; ++d) s += q_sh[qi * 32 + d] * kv[d * 257 + t];
      s = s / SQRT_HD;
      float m = s;
#pragma unroll
      for (int o = 32; o; o >>= 1) m = fmaxf(m, __shfl_xor(m, o));
      if ((t & 63) == 0) red[t >> 6] = m;
      __syncthreads();
      m = fmaxf(fmaxf(red[0], red[1]), fmaxf(red[2], red[3]));
      float ev = expf(s - m);
      float z = ev;
#pragma unroll
      for (int o = 32; o; o >>= 1) z += __shfl_xor(z, o);
      if ((t & 63) == 0) red[4 + (t >> 6)] = z;
      __syncthreads();
      z = red[4] + red[5] + red[6] + red[7];
      p_all[qi * 256 + t] = ev / z;
      __syncthreads();
    }
    // V phase — overwrite kv
    for (int j = t; j < 8192; j += 256) {
      int a = j >> 5, d = j & 31;
      kv[a * 32 + d] = Vb[a * 256 + hoff + d];
    }
    __syncthreads();
    for (int qi = 0; qi < 16; ++qi) {
      const int grp = t >> 5, d = t & 31;
      float acc = 0.0f;
#pragma unroll
      for (int i = 0; i < 32; ++i) {
        int a = grp * 32 + i;
        acc += p_all[qi * 256 + a] * kv[a * 32 + d];
      }
      part[grp * 32 + d] = acc;
      __syncthreads();
      if (t < 32) {
        float o = 0.0f;
#pragma unroll
        for (int g = 0; g < 8; ++g) o += part[g * 32 + t];
        O[((size_t)b * MAXQ + q0 + qi) * 256 + hoff + t] = o;
      }
      __syncthreads();
    }
  }
}

// ---------------------------------------------------------------------------
extern "C" void kernel_launch(void* const* d_in, const int* in_sizes, int n_in,
                              void* d_out, int out_size, void* d_ws, size_t ws_size,
                              hipStream_t stream) {
  const float* density = (const float*)d_in[0];
  const float* pcount  = (const float*)d_in[1];
  const float* mem     = (const float*)d_in[2];
  const float* af      = (const float*)d_in[3];
  const float* pw1     = (const float*)d_in[4];
  const float* pb1     = (const float*)d_in[5];
  const float* pw2     = (const float*)d_in[6];
  const float* pb2     = (const float*)d_in[7];
  const float* inw     = (const float*)d_in[8];
  const float* inb     = (const float*)d_in[9];
  const float* outw    = (const float*)d_in[10];
  const float* outb    = (const float*)d_in[11];
  const float* qw      = (const float*)d_in[12];
  const float* qb      = (const float*)d_in[13];

  float* out = (float*)d_out;
  float* ws = (float*)d_ws;

  // ws layout (floats)
  float* positions  = ws;                          // 25,600
  float* sampled    = ws + 32768;                  // 3,276,800 (becomes Q in-place)
  float* attn_out   = sampled + 3276800;           // 3,276,800
  float* agent_init = attn_out + 3276800;          // 1,048,576
  float* Km         = agent_init + 1048576;        // 1,048,576
  float* Vm         = Km + 1048576;                // 1,048,576
  int*   nq_i       = (int*)(Vm + 1048576);        // 16

  float* out_queries = out;                        // 3,276,800
  float* out_qpos    = out + 3276800;              // 3,276,800
  float* out_nq      = out + 6553600;              // 16
  float* out_mask    = out + 6553616;              // 12,800

  nq_kernel<<<1, 64, 0, stream>>>(pcount, nq_i, out_nq);
  sample_kernel<<<BQ, 256, 0, stream>>>(density, nq_i, positions, out_mask);
  posmlp_kernel<<<BQ / 16, 256, 0, stream>>>(positions, pw1, pb1, pw2, pb2, out_qpos);
  bilinear_kernel<<<BQ, 256, 0, stream>>>(mem, positions, sampled);
  agent_init_kernel<<<4096 / 32, 256, 0, stream>>>(af, qw, qb, agent_init);
  // Q = sampled @ Wq^T + bq (in-place)
  proj_kernel<<<BQ / 16, 256, 0, stream>>>(sampled, inw, inb, nullptr, sampled);
  // K, V from agent_init
  proj_kernel<<<4096 / 16, 256, 0, stream>>>(agent_init, inw + 256 * 256, inb + 256, nullptr, Km);
  proj_kernel<<<4096 / 16, 256, 0, stream>>>(agent_init, inw + 512 * 256, inb + 512, nullptr, Vm);
  attn_kernel<<<(NB) * 50, 256, 0, stream>>>(sampled, Km, Vm, attn_out);
  // queries = attn_out @ out_w^T + out_b + query_pos
  proj_kernel<<<BQ / 16, 256, 0, stream>>>(attn_out, outw, outb, out_qpos, out_queries);
}

// Round 2
// 782.283 us; speedup vs baseline: 1.5861x; 1.5861x over previous
//
#include <hip/hip_runtime.h>
#include <stdint.h>
#include <math.h>

#define NB 16
#define HD_ 80
#define WD_ 80
#define HWD 6400
#define MAXQ 800
#define EMB 256
#define NMEM 8400
#define BQ (NB*MAXQ)          // 12800

// ---------------------------------------------------------------------------
// Threefry2x32 with key (0, 42) — bit-exact with jax.random.key(42),
// partitionable scheme: bits(f) = o0 ^ o1, x0 = hi32(f) = 0 (f < 2^32 here).
__device__ __forceinline__ void tf2x32(uint32_t x0, uint32_t x1,
                                       uint32_t& o0, uint32_t& o1) {
  const uint32_t ks0 = 0u;
  const uint32_t ks1 = 42u;
  const uint32_t ks2 = 0x1BD11BDAu ^ 0u ^ 42u;
  x0 += ks0; x1 += ks1;
#define TF_ROT(r) { x0 += x1; x1 = (x1 << (r)) | (x1 >> (32 - (r))); x1 ^= x0; }
  TF_ROT(13) TF_ROT(15) TF_ROT(26) TF_ROT(6)
  x0 += ks1; x1 += ks2 + 1u;
  TF_ROT(17) TF_ROT(29) TF_ROT(16) TF_ROT(24)
  x0 += ks2; x1 += ks0 + 2u;
  TF_ROT(13) TF_ROT(15) TF_ROT(26) TF_ROT(6)
  x0 += ks0; x1 += ks1 + 3u;
  TF_ROT(17) TF_ROT(29) TF_ROT(16) TF_ROT(24)
  x0 += ks1; x1 += ks2 + 4u;
  TF_ROT(13) TF_ROT(15) TF_ROT(26) TF_ROT(6)
  x0 += ks2; x1 += ks0 + 5u;
#undef TF_ROT
  o0 = x0; o1 = x1;
}

// ---------------------------------------------------------------------------
__global__ void nq_kernel(const float* __restrict__ pc, int* __restrict__ nq_i,
                          float* __restrict__ out_nq) {
  int t = threadIdx.x;
  if (t < NB) {
    float v = floorf(pc[t] * 2.0f);
    int n = (int)v;
    n = n < 100 ? 100 : (n > 800 ? 800 : n);
    nq_i[t] = n;
    out_nq[t] = (float)n;
  }
}

// lgs = density / 0.1f  (bit-exact same divide as reference, hoisted out of
// the 82M-element sampling loop)
__global__ __launch_bounds__(256)
void scale_kernel(const float* __restrict__ density, float* __restrict__ lgs) {
  int i = blockIdx.x * 256 + threadIdx.x;
  if (i < NB * HWD) lgs[i] = density[i] / 0.1f;
}

// ---------------------------------------------------------------------------
// Gumbel-max categorical sampling. One block per (b,q); argmax over 6400.
__global__ __launch_bounds__(256)
void sample_kernel(const float* __restrict__ lgs, const int* __restrict__ nq_i,
                   float* __restrict__ positions, float* __restrict__ mask_out) {
  __shared__ float swv[4];
  __shared__ int   swi[4];
  const int bq = blockIdx.x;
  const int b = bq / MAXQ;
  const int q = bq - b * MAXQ;
  const int t = threadIdx.x;
  const float* lg = lgs + b * HWD;
  const uint32_t base = (uint32_t)bq * (uint32_t)HWD;  // < 2^32

  float best = -3.0e38f;
  int besti = HWD;
#pragma unroll 5
  for (int i = 0; i < 25; ++i) {
    int c = t + (i << 8);
    uint32_t o0, o1;
    tf2x32(0u, base + (uint32_t)c, o0, o1);
    uint32_t bits = o0 ^ o1;
    uint32_t mant = (bits >> 9) | 0x3f800000u;
    float u = __uint_as_float(mant) - 1.0f;
    if (u == 0.0f) u = 1.17549435e-38f;  // finfo(f32).tiny
    float g = -logf(-logf(u));
    float val = g + lg[c];
    if (val > best) { best = val; besti = c; }  // per-thread c ascending
  }
  // wave-level argmax (value desc, index asc on ties)
#pragma unroll
  for (int off = 32; off; off >>= 1) {
    float ov = __shfl_xor(best, off);
    int   oi = __shfl_xor(besti, off);
    if (ov > best || (ov == best && oi < besti)) { best = ov; besti = oi; }
  }
  if ((t & 63) == 0) { swv[t >> 6] = best; swi[t >> 6] = besti; }
  __syncthreads();
  if (t == 0) {
    float bv = swv[0]; int bi = swi[0];
#pragma unroll
    for (int w = 1; w < 4; ++w) {
      float ov = swv[w]; int oi = swi[w];
      if (ov > bv || (ov == bv && oi < bi)) { bv = ov; bi = oi; }
    }
    int n = nq_i[b];
    float px, py;
    if (q >= n) { px = 0.0f; py = 0.0f; }
    else {
      py = (float)(bi / WD_) / 80.0f;
      px = (float)(bi % WD_) / 80.0f;
    }
    positions[2 * bq]     = px;
    positions[2 * bq + 1] = py;
    mask_out[bq] = (q >= n) ? 1.0f : 0.0f;
  }
}

// ---------------------------------------------------------------------------
__device__ __forceinline__ float gelu_tanh(float x) {
  float x3 = x * x * x;
  float inner = 0.7978845608028654f * (x + 0.044715f * x3);
  float cdf = 0.5f * (1.0f + tanhf(inner));
  return x * cdf;
}

__global__ __launch_bounds__(256)
void posmlp_kernel(const float* __restrict__ positions,
                   const float* __restrict__ w1, const float* __restrict__ b1,
                   const float* __restrict__ w2, const float* __restrict__ b2,
                   float* __restrict__ qpos) {
  __shared__ float ppos[16][2];
  __shared__ float h_all[16 * 128];
  const int t = threadIdx.x;
  const size_t q0 = (size_t)blockIdx.x * 16;
  if (t < 32) ppos[t >> 1][t & 1] = positions[q0 * 2 + t];
  __syncthreads();
  for (int j = t; j < 2048; j += 256) {
    int qi = j >> 7, k = j & 127;
    float x = ppos[qi][0] * w1[k] + ppos[qi][1] * w1[128 + k] + b1[k];
    h_all[j] = gelu_tanh(x);
  }
  __syncthreads();
  float acc[16];
#pragma unroll
  for (int qi = 0; qi < 16; ++qi) acc[qi] = 0.0f;
  for (int k = 0; k < 128; ++k) {
    float wv = w2[k * 256 + t];
#pragma unroll
    for (int qi = 0; qi < 16; ++qi) acc[qi] += h_all[qi * 128 + k] * wv;
  }
  float bv = b2[t];
#pragma unroll
  for (int qi = 0; qi < 16; ++qi)
    qpos[(q0 + qi) * 256 + t] = acc[qi] + bv;
}

// ---------------------------------------------------------------------------
__device__ __forceinline__ float bil_corner(const float* __restrict__ fmb,
                                            int yy, int xx, int e) {
  if (yy < 0 || yy >= HD_ || xx < 0 || xx >= WD_) return 0.0f;
  return fmb[((size_t)(yy * WD_ + xx)) * EMB + e];
}

__global__ __launch_bounds__(256)
void bilinear_kernel(const float* __restrict__ mem,
                     const float* __restrict__ positions,
                     float* __restrict__ sampled) {
  const int bq = blockIdx.x;
  const int b = bq / MAXQ;
  const int e = threadIdx.x;
  float px = positions[2 * bq], py = positions[2 * bq + 1];
  float gx = px * 2.0f - 1.0f;
  float gy = py * 2.0f - 1.0f;
  float x = (gx + 1.0f) * 0.5f * 80.0f - 0.5f;
  float y = (gy + 1.0f) * 0.5f * 80.0f - 0.5f;
  float x0f = floorf(x), y0f = floorf(y);
  float wx1 = x - x0f, wx0 = 1.0f - wx1;
  float wy1 = y - y0f, wy0 = 1.0f - wy1;
  int x0 = (int)x0f, y0 = (int)y0f;
  int x1 = x0 + 1, y1 = y0 + 1;
  const float* fmb = mem + (size_t)b * NMEM * EMB;
  float acc;
  acc  = bil_corner(fmb, y0, x0, e) * (wy0 * wx0);
  acc += bil_corner(fmb, y0, x1, e) * (wy0 * wx1);
  acc += bil_corner(fmb, y1, x0, e) * (wy1 * wx0);
  acc += bil_corner(fmb, y1, x1, e) * (wy1 * wx1);
  sampled[(size_t)bq * EMB + e] = acc;
}

// ---------------------------------------------------------------------------
__global__ __launch_bounds__(256)
void agent_init_kernel(const float* __restrict__ af, const float* __restrict__ qw,
                       const float* __restrict__ qb, float* __restrict__ out) {
  __shared__ float xs[32 * 64];
  const int t = threadIdx.x;
  const size_t r0 = (size_t)blockIdx.x * 32;
  for (int j = t; j < 32 * 64; j += 256) xs[j] = af[r0 * 64 + j];
  __syncthreads();
  float acc[32];
#pragma unroll
  for (int r = 0; r < 32; ++r) acc[r] = 0.0f;
  for (int k = 0; k < 64; ++k) {
    float wv = qw[k * 256 + t];
#pragma unroll
    for (int r = 0; r < 32; ++r) acc[r] += xs[r * 64 + k] * wv;
  }
  float bv = qb[t];
#pragma unroll
  for (int r = 0; r < 32; ++r)
    out[(r0 + r) * 256 + t] = acc[r] + bv;
}

// ---------------------------------------------------------------------------
// Register-tiled fp32 GEMM: out[r][e] = sum_k X[r][k] * W[e][k] + bias[e]
// (+ add[r][e]). Tile 64 rows x 64 cols, thread 4x4, K chunks of 32.
// Ws is XOR-swizzled (salt 4*((c>>2)&7)) so the 16-lane column reads spread
// across all 8 bank groups (2-way max).
__global__ __launch_bounds__(256)
void gemm_kernel(const float* __restrict__ X, const float* __restrict__ W,
                 const float* __restrict__ bias, const float* __restrict__ add,
                 float* __restrict__ out) {
  __shared__ float Xs[64 * 36];
  __shared__ float Ws[64 * 36];
  const int t = threadIdx.x;
  const int tc = t & 15, tr = t >> 4;
  const size_t row0 = (size_t)blockIdx.x * 64;
  const int col0 = blockIdx.y * 64;
  float acc[4][4] = {};
  for (int kt = 0; kt < 8; ++kt) {
    __syncthreads();
#pragma unroll
    for (int p = 0; p < 2; ++p) {
      int j4 = t + p * 256;              // 0..511
      int r = j4 >> 3, kq = j4 & 7;
      float4 xv = *(const float4*)&X[(row0 + r) * 256 + kt * 32 + kq * 4];
      *(float4*)&Xs[r * 36 + kq * 4] = xv;
      float4 wv = *(const float4*)&W[(size_t)(col0 + r) * 256 + kt * 32 + kq * 4];
      *(float4*)&Ws[r * 36 + ((kq * 4) ^ (4 * ((r >> 2) & 7)))] = wv;
    }
    __syncthreads();
#pragma unroll
    for (int kq = 0; kq < 8; ++kq) {
      float4 xv[4], wv[4];
#pragma unroll
      for (int i = 0; i < 4; ++i)
        xv[i] = *(const float4*)&Xs[(tr * 4 + i) * 36 + kq * 4];
#pragma unroll
      for (int j = 0; j < 4; ++j)
        wv[j] = *(const float4*)&Ws[(tc * 4 + j) * 36 + ((kq * 4) ^ (4 * (tc & 7)))];
#pragma unroll
      for (int i = 0; i < 4; ++i)
#pragma unroll
        for (int j = 0; j < 4; ++j)
          acc[i][j] += xv[i].x * wv[j].x + xv[i].y * wv[j].y
                     + xv[i].z * wv[j].z + xv[i].w * wv[j].w;
    }
  }
  float4 bv = *(const float4*)&bias[col0 + tc * 4];
#pragma unroll
  for (int i = 0; i < 4; ++i) {
    size_t row = row0 + tr * 4 + i;
    float4 v;
    v.x = acc[i][0] + bv.x; v.y = acc[i][1] + bv.y;
    v.z = acc[i][2] + bv.z; v.w = acc[i][3] + bv.w;
    if (add) {
      float4 av = *(const float4*)&add[row * 256 + col0 + tc * 4];
      v.x += av.x; v.y += av.y; v.z += av.z; v.w += av.w;
    }
    *(float4*)&out[row * 256 + col0 + tc * 4] = v;
  }
}

// ---------------------------------------------------------------------------
// Cross-attention, one query per thread, in-place O over Q.
// grid (qtile=13, head=8, batch=16), block 64. K/V rows are lane-uniform
// broadcast loads (L2-hot: 2 MB total), double-buffered by unroll-2.
#define LOADKV(kd, vd, a) {                                        \
  const float4* kp = Kb4 + (size_t)(a) * 64;                       \
  const float4* vp = Vb4 + (size_t)(a) * 64;                       \
  _Pragma("unroll") for (int j = 0; j < 8; ++j) { kd[j] = kp[j]; vd[j] = vp[j]; } }

#define ASTEP(kk, vv) {                                            \
  float s0 = 0.f, s1 = 0.f, s2 = 0.f, s3 = 0.f;                    \
  _Pragma("unroll") for (int j = 0; j < 8; ++j) {                  \
    s0 += qv[j].x * kk[j].x; s1 += qv[j].y * kk[j].y;              \
    s2 += qv[j].z * kk[j].z; s3 += qv[j].w * kk[j].w; }            \
  float s = ((s0 + s1) + (s2 + s3)) * 0.17677669529663689f;        \
  if (s > m + 8.0f) {                                              \
    float r = expf(m - s);                                         \
    z = z * r + 1.0f;                                              \
    _Pragma("unroll") for (int j = 0; j < 8; ++j) {                \
      o[j].x = o[j].x * r + vv[j].x; o[j].y = o[j].y * r + vv[j].y;\
      o[j].z = o[j].z * r + vv[j].z; o[j].w = o[j].w * r + vv[j].w; } \
    m = s;                                                         \
  } else {                                                         \
    float p = expf(s - m);                                         \
    z += p;                                                        \
    _Pragma("unroll") for (int j = 0; j < 8; ++j) {                \
      o[j].x += p * vv[j].x; o[j].y += p * vv[j].y;                \
      o[j].z += p * vv[j].z; o[j].w += p * vv[j].w; } } }

__global__ __launch_bounds__(64)
void attn_kernel(float* __restrict__ QO, const float* __restrict__ Km,
                 const float* __restrict__ Vm) {
  const int tile = blockIdx.x, h = blockIdx.y, b = blockIdx.z;
  const int t = threadIdx.x;
  const int q = tile * 64 + t;
  const bool valid = q < MAXQ;
  const int qc = valid ? q : MAXQ - 1;
  float4* Qrow = (float4*)(QO + ((size_t)(b * MAXQ + qc)) * 256 + h * 32);
  const float4* Kb4 = (const float4*)(Km + (size_t)b * 256 * 256 + h * 32);
  const float4* Vb4 = (const float4*)(Vm + (size_t)b * 256 * 256 + h * 32);

  float4 qv[8];
#pragma unroll
  for (int j = 0; j < 8; ++j) qv[j] = Qrow[j];

  float4 o[8];
#pragma unroll
  for (int j = 0; j < 8; ++j) o[j] = make_float4(0.f, 0.f, 0.f, 0.f);
  float m = -3.0e38f, z = 0.0f;

  float4 ka[8], va[8], kb[8], vb[8];
  LOADKV(ka, va, 0);
  for (int a2 = 0; a2 < 128; ++a2) {
    const int a = a2 * 2;
    LOADKV(kb, vb, a + 1);
    ASTEP(ka, va);
    if (a2 < 127) { LOADKV(ka, va, a + 2); }
    ASTEP(kb, vb);
  }

  if (valid) {
    float zi = 1.0f / z;
#pragma unroll
    for (int j = 0; j < 8; ++j) {
      float4 v;
      v.x = o[j].x * zi; v.y = o[j].y * zi;
      v.z = o[j].z * zi; v.w = o[j].w * zi;
      Qrow[j] = v;
    }
  }
}

// ---------------------------------------------------------------------------
extern "C" void kernel_launch(void* const* d_in, const int* in_sizes, int n_in,
                              void* d_out, int out_size, void* d_ws, size_t ws_size,
                              hipStream_t stream) {
  const float* density = (const float*)d_in[0];
  const float* pcount  = (const float*)d_in[1];
  const float* mem     = (const float*)d_in[2];
  const float* af      = (const float*)d_in[3];
  const float* pw1     = (const float*)d_in[4];
  const float* pb1     = (const float*)d_in[5];
  const float* pw2     = (const float*)d_in[6];
  const float* pb2     = (const float*)d_in[7];
  const float* inw     = (const float*)d_in[8];
  const float* inb     = (const float*)d_in[9];
  const float* outw    = (const float*)d_in[10];
  const float* outb    = (const float*)d_in[11];
  const float* qw      = (const float*)d_in[12];
  const float* qb      = (const float*)d_in[13];

  float* out = (float*)d_out;
  float* ws = (float*)d_ws;

  // ws layout (floats)
  float* positions  = ws;                          // 25,600 (pad 32,768)
  float* lgs        = ws + 32768;                  // 102,400 (pad to 139,264 start)
  float* sampled    = ws + 139264;                 // 3,276,800
  float* Qbuf       = sampled + 3276800;           // 3,276,800 (Q, then content in-place)
  float* agent_init = Qbuf + 3276800;              // 1,048,576
  float* Km         = agent_init + 1048576;        // 1,048,576
  float* Vm         = Km + 1048576;                // 1,048,576
  int*   nq_i       = (int*)(Vm + 1048576);        // 16

  float* out_queries = out;                        // 3,276,800
  float* out_qpos    = out + 3276800;              // 3,276,800
  float* out_nq      = out + 6553600;              // 16
  float* out_mask    = out + 6553616;              // 12,800

  nq_kernel<<<1, 64, 0, stream>>>(pcount, nq_i, out_nq);
  scale_kernel<<<(NB * HWD + 255) / 256, 256, 0, stream>>>(density, lgs);
  sample_kernel<<<BQ, 256, 0, stream>>>(lgs, nq_i, positions, out_mask);
  posmlp_kernel<<<BQ / 16, 256, 0, stream>>>(positions, pw1, pb1, pw2, pb2, out_qpos);
  bilinear_kernel<<<BQ, 256, 0, stream>>>(mem, positions, sampled);
  agent_init_kernel<<<4096 / 32, 256, 0, stream>>>(af, qw, qb, agent_init);
  // Q = sampled @ Wq^T + bq
  gemm_kernel<<<dim3(BQ / 64, 4), 256, 0, stream>>>(sampled, inw, inb, nullptr, Qbuf);
  // K, V from agent_init
  gemm_kernel<<<dim3(4096 / 64, 4), 256, 0, stream>>>(agent_init, inw + 256 * 256, inb + 256, nullptr, Km);
  gemm_kernel<<<dim3(4096 / 64, 4), 256, 0, stream>>>(agent_init, inw + 512 * 256, inb + 512, nullptr, Vm);
  // content (in-place over Qbuf)
  attn_kernel<<<dim3(13, 8, NB), 64, 0, stream>>>(Qbuf, Km, Vm);
  // queries = content @ out_w^T + out_b + query_pos
  gemm_kernel<<<dim3(BQ / 64, 4), 256, 0, stream>>>(Qbuf, outw, outb, out_qpos, out_queries);
}

// Round 4
// 733.673 us; speedup vs baseline: 1.6912x; 1.0663x over previous
//
#include <hip/hip_runtime.h>
#include <stdint.h>
#include <math.h>

#define NB 16
#define HD_ 80
#define WD_ 80
#define HWD 6400
#define MAXQ 800
#define EMB 256
#define NMEM 8400
#define BQ (NB*MAXQ)          // 12800

// ---------------------------------------------------------------------------
// Threefry2x32 with key (0, 42) — bit-exact with jax.random.key(42),
// partitionable scheme: bits(f) = o0 ^ o1, x0 = hi32(f) = 0 (f < 2^32 here).
__device__ __forceinline__ void tf2x32(uint32_t x0, uint32_t x1,
                                       uint32_t& o0, uint32_t& o1) {
  const uint32_t ks0 = 0u;
  const uint32_t ks1 = 42u;
  const uint32_t ks2 = 0x1BD11BDAu ^ 0u ^ 42u;
  x0 += ks0; x1 += ks1;
#define TF_ROT(r) { x0 += x1; x1 = (x1 << (r)) | (x1 >> (32 - (r))); x1 ^= x0; }
  TF_ROT(13) TF_ROT(15) TF_ROT(26) TF_ROT(6)
  x0 += ks1; x1 += ks2 + 1u;
  TF_ROT(17) TF_ROT(29) TF_ROT(16) TF_ROT(24)
  x0 += ks2; x1 += ks0 + 2u;
  TF_ROT(13) TF_ROT(15) TF_ROT(26) TF_ROT(6)
  x0 += ks0; x1 += ks1 + 3u;
  TF_ROT(17) TF_ROT(29) TF_ROT(16) TF_ROT(24)
  x0 += ks1; x1 += ks2 + 4u;
  TF_ROT(13) TF_ROT(15) TF_ROT(26) TF_ROT(6)
  x0 += ks2; x1 += ks0 + 5u;
#undef TF_ROT
  o0 = x0; o1 = x1;
}

// ---------------------------------------------------------------------------
// prep: nq (+float copy out) and lg table = density / 0.1 (hoisted divide)
__global__ __launch_bounds__(256)
void prep_kernel(const float* __restrict__ pc, int* __restrict__ nq_i,
                 float* __restrict__ out_nq,
                 const float* __restrict__ density, float* __restrict__ lgtab) {
  int i = blockIdx.x * 256 + threadIdx.x;
  if (i < NB * HWD) lgtab[i] = density[i] / 0.1f;
  if (i < NB) {
    float v = floorf(pc[i] * 2.0f);
    int n = (int)v;
    n = n < 100 ? 100 : (n > 800 ? 800 : n);
    nq_i[i] = n;
    out_nq[i] = (float)n;
  }
}

// ---------------------------------------------------------------------------
// Gumbel-max categorical sampling. One block per (b,q); argmax over 6400.
// Gumbel computed with 2 hardware v_log_f32:
//   u = bits-to-[0,1);  e = -ln(u) = -ln2*log2(u);  g+lg = lg - ln2*log2(e)
// u==0 -> log2(u)=-inf -> e=+inf -> val=-inf (never selected; matches ref
// where the tiny-clamped candidate also never wins the argmax).
__global__ __launch_bounds__(256)
void sample_kernel(const float* __restrict__ lgs, const int* __restrict__ nq_i,
                   float* __restrict__ positions, float* __restrict__ mask_out) {
  __shared__ float swv[4];
  __shared__ int   swi[4];
  const int bq = blockIdx.x;
  const int b = bq / MAXQ;
  const int q = bq - b * MAXQ;
  const int t = threadIdx.x;
  const float* lg = lgs + b * HWD;
  const uint32_t base = (uint32_t)bq * (uint32_t)HWD;  // < 2^32

  const float NLN2 = -0.69314718055994530942f;
  float best = -3.0e38f;
  int besti = HWD;
#pragma unroll 5
  for (int i = 0; i < 25; ++i) {
    int c = t + (i << 8);
    uint32_t o0, o1;
    tf2x32(0u, base + (uint32_t)c, o0, o1);
    uint32_t bits = o0 ^ o1;
    float u = __uint_as_float((bits >> 9) | 0x3f800000u) - 1.0f;
    float l2;
    asm("v_log_f32 %0, %1" : "=v"(l2) : "v"(u));   // log2(u) <= 0
    float e = NLN2 * l2;                           // -ln(u) >= 0
    float l3;
    asm("v_log_f32 %0, %1" : "=v"(l3) : "v"(e));   // log2(e)
    float val = fmaf(NLN2, l3, lg[c]);             // g + lg
    if (val > best) { best = val; besti = c; }     // per-thread c ascending
  }
  // wave-level argmax (value desc, index asc on ties)
#pragma unroll
  for (int off = 32; off; off >>= 1) {
    float ov = __shfl_xor(best, off);
    int   oi = __shfl_xor(besti, off);
    if (ov > best || (ov == best && oi < besti)) { best = ov; besti = oi; }
  }
  if ((t & 63) == 0) { swv[t >> 6] = best; swi[t >> 6] = besti; }
  __syncthreads();
  if (t == 0) {
    float bv = swv[0]; int bi = swi[0];
#pragma unroll
    for (int w = 1; w < 4; ++w) {
      float ov = swv[w]; int oi = swi[w];
      if (ov > bv || (ov == bv && oi < bi)) { bv = ov; bi = oi; }
    }
    int n = nq_i[b];
    float px, py;
    if (q >= n) { px = 0.0f; py = 0.0f; }
    else {
      py = (float)(bi / WD_) / 80.0f;
      px = (float)(bi % WD_) / 80.0f;
    }
    positions[2 * bq]     = px;
    positions[2 * bq + 1] = py;
    mask_out[bq] = (q >= n) ? 1.0f : 0.0f;
  }
}

// ---------------------------------------------------------------------------
__device__ __forceinline__ float gelu_tanh(float x) {
  float x3 = x * x * x;
  float inner = 0.7978845608028654f * (x + 0.044715f * x3);
  float cdf = 0.5f * (1.0f + tanhf(inner));
  return x * cdf;
}

__global__ __launch_bounds__(256)
void posmlp_kernel(const float* __restrict__ positions,
                   const float* __restrict__ w1, const float* __restrict__ b1,
                   const float* __restrict__ w2, const float* __restrict__ b2,
                   float* __restrict__ qpos) {
  __shared__ float ppos[16][2];
  __shared__ float h_all[16 * 128];
  const int t = threadIdx.x;
  const size_t q0 = (size_t)blockIdx.x * 16;
  if (t < 32) ppos[t >> 1][t & 1] = positions[q0 * 2 + t];
  __syncthreads();
  for (int j = t; j < 2048; j += 256) {
    int qi = j >> 7, k = j & 127;
    float x = ppos[qi][0] * w1[k] + ppos[qi][1] * w1[128 + k] + b1[k];
    h_all[j] = gelu_tanh(x);
  }
  __syncthreads();
  float acc[16];
#pragma unroll
  for (int qi = 0; qi < 16; ++qi) acc[qi] = 0.0f;
  for (int k = 0; k < 128; ++k) {
    float wv = w2[k * 256 + t];
#pragma unroll
    for (int qi = 0; qi < 16; ++qi) acc[qi] += h_all[qi * 128 + k] * wv;
  }
  float bv = b2[t];
#pragma unroll
  for (int qi = 0; qi < 16; ++qi)
    qpos[(q0 + qi) * 256 + t] = acc[qi] + bv;
}

// ---------------------------------------------------------------------------
// Bilinear grid_sample, float4-vectorized: 64 threads per query, 4 channels
// per thread. FP weight chain replicated exactly from the reference.
__global__ __launch_bounds__(64)
void bilinear_kernel(const float* __restrict__ mem,
                     const float* __restrict__ positions,
                     float* __restrict__ sampled) {
  const int bq = blockIdx.x;
  const int b = bq / MAXQ;
  const int t = threadIdx.x;                 // float4 channel group 0..63
  float px = positions[2 * bq], py = positions[2 * bq + 1];
  float gx = px * 2.0f - 1.0f;
  float gy = py * 2.0f - 1.0f;
  float x = (gx + 1.0f) * 0.5f * 80.0f - 0.5f;
  float y = (gy + 1.0f) * 0.5f * 80.0f - 0.5f;
  float x0f = floorf(x), y0f = floorf(y);
  float wx1 = x - x0f, wx0 = 1.0f - wx1;
  float wy1 = y - y0f, wy0 = 1.0f - wy1;
  int x0 = (int)x0f, y0 = (int)y0f;
  int x1 = x0 + 1, y1 = y0 + 1;
  const float4* fmb = (const float4*)(mem + (size_t)b * NMEM * EMB);
  float4 acc = make_float4(0.f, 0.f, 0.f, 0.f);
#define BIL_CORNER(yy, xx, wt) \
  if ((yy) >= 0 && (yy) < HD_ && (xx) >= 0 && (xx) < WD_) {            \
    float4 v = fmb[(size_t)((yy) * WD_ + (xx)) * 64 + t];              \
    acc.x += (wt) * v.x; acc.y += (wt) * v.y;                          \
    acc.z += (wt) * v.z; acc.w += (wt) * v.w; }
  BIL_CORNER(y0, x0, wy0 * wx0)
  BIL_CORNER(y0, x1, wy0 * wx1)
  BIL_CORNER(y1, x0, wy1 * wx0)
  BIL_CORNER(y1, x1, wy1 * wx1)
#undef BIL_CORNER
  ((float4*)sampled)[(size_t)bq * 64 + t] = acc;
}

// ---------------------------------------------------------------------------
__global__ __launch_bounds__(256)
void agent_init_kernel(const float* __restrict__ af, const float* __restrict__ qw,
                       const float* __restrict__ qb, float* __restrict__ out) {
  __shared__ float xs[32 * 64];
  const int t = threadIdx.x;
  const size_t r0 = (size_t)blockIdx.x * 32;
  for (int j = t; j < 32 * 64; j += 256) xs[j] = af[r0 * 64 + j];
  __syncthreads();
  float acc[32];
#pragma unroll
  for (int r = 0; r < 32; ++r) acc[r] = 0.0f;
  for (int k = 0; k < 64; ++k) {
    float wv = qw[k * 256 + t];
#pragma unroll
    for (int r = 0; r < 32; ++r) acc[r] += xs[r * 64 + k] * wv;
  }
  float bv = qb[t];
#pragma unroll
  for (int r = 0; r < 32; ++r)
    out[(r0 + r) * 256 + t] = acc[r] + bv;
}

// ---------------------------------------------------------------------------
// Register-tiled fp32 GEMM: out[r][c] = sum_k X[r][k]*W[c][k] + bias[c]
// (+ add). ldx/ldc generalize input/output row strides (K fixed at 256).
__global__ __launch_bounds__(256)
void gemm_kernel(const float* __restrict__ X, int ldx,
                 const float* __restrict__ W,
                 const float* __restrict__ bias, const float* __restrict__ add,
                 float* __restrict__ out, int ldc) {
  __shared__ float Xs[64 * 36];
  __shared__ float Ws[64 * 36];
  const int t = threadIdx.x;
  const int tc = t & 15, tr = t >> 4;
  const size_t row0 = (size_t)blockIdx.x * 64;
  const int col0 = blockIdx.y * 64;
  float acc[4][4] = {};
  for (int kt = 0; kt < 8; ++kt) {
    __syncthreads();
#pragma unroll
    for (int p = 0; p < 2; ++p) {
      int j4 = t + p * 256;              // 0..511
      int r = j4 >> 3, kq = j4 & 7;
      float4 xv = *(const float4*)&X[(row0 + r) * ldx + kt * 32 + kq * 4];
      *(float4*)&Xs[r * 36 + kq * 4] = xv;
      float4 wv = *(const float4*)&W[(size_t)(col0 + r) * 256 + kt * 32 + kq * 4];
      *(float4*)&Ws[r * 36 + ((kq * 4) ^ (4 * ((r >> 2) & 7)))] = wv;
    }
    __syncthreads();
#pragma unroll
    for (int kq = 0; kq < 8; ++kq) {
      float4 xv[4], wv[4];
#pragma unroll
      for (int i = 0; i < 4; ++i)
        xv[i] = *(const float4*)&Xs[(tr * 4 + i) * 36 + kq * 4];
#pragma unroll
      for (int j = 0; j < 4; ++j)
        wv[j] = *(const float4*)&Ws[(tc * 4 + j) * 36 + ((kq * 4) ^ (4 * (tc & 7)))];
#pragma unroll
      for (int i = 0; i < 4; ++i)
#pragma unroll
        for (int j = 0; j < 4; ++j)
          acc[i][j] += xv[i].x * wv[j].x + xv[i].y * wv[j].y
                     + xv[i].z * wv[j].z + xv[i].w * wv[j].w;
    }
  }
  float4 bv = *(const float4*)&bias[col0 + tc * 4];
#pragma unroll
  for (int i = 0; i < 4; ++i) {
    size_t row = row0 + tr * 4 + i;
    float4 v;
    v.x = acc[i][0] + bv.x; v.y = acc[i][1] + bv.y;
    v.z = acc[i][2] + bv.z; v.w = acc[i][3] + bv.w;
    if (add) {
      float4 av = *(const float4*)&add[row * 256 + col0 + tc * 4];
      v.x += av.x; v.y += av.y; v.z += av.z; v.w += av.w;
    }
    *(float4*)&out[row * ldc + col0 + tc * 4] = v;
  }
}

// ---------------------------------------------------------------------------
// Cross-attention, one query per thread, in-place O over Q.
// K/V interleaved in one [4096][512] buffer (K cols 0..255, V cols 256..511);
// float4 row stride 128.
#define KVLD4 128
#define LOADKV(kd, vd, a) {                                        \
  const float4* kp = Kb4 + (size_t)(a) * KVLD4;                    \
  const float4* vp = kp + 64;                                      \
  _Pragma("unroll") for (int j = 0; j < 8; ++j) { kd[j] = kp[j]; vd[j] = vp[j]; } }

#define ASTEP(kk, vv) {                                            \
  float s0 = 0.f, s1 = 0.f, s2 = 0.f, s3 = 0.f;                    \
  _Pragma("unroll") for (int j = 0; j < 8; ++j) {                  \
    s0 += qv[j].x * kk[j].x; s1 += qv[j].y * kk[j].y;              \
    s2 += qv[j].z * kk[j].z; s3 += qv[j].w * kk[j].w; }            \
  float s = ((s0 + s1) + (s2 + s3)) * 0.17677669529663689f;        \
  if (s > m + 8.0f) {                                              \
    float r = expf(m - s);                                         \
    z = z * r + 1.0f;                                              \
    _Pragma("unroll") for (int j = 0; j < 8; ++j) {                \
      o[j].x = o[j].x * r + vv[j].x; o[j].y = o[j].y * r + vv[j].y;\
      o[j].z = o[j].z * r + vv[j].z; o[j].w = o[j].w * r + vv[j].w; } \
    m = s;                                                         \
  } else {                                                         \
    float p = expf(s - m);                                         \
    z += p;                                                        \
    _Pragma("unroll") for (int j = 0; j < 8; ++j) {                \
      o[j].x += p * vv[j].x; o[j].y += p * vv[j].y;                \
      o[j].z += p * vv[j].z; o[j].w += p * vv[j].w; } } }

__global__ __launch_bounds__(64)
void attn_kernel(float* __restrict__ QO, const float* __restrict__ KV) {
  const int tile = blockIdx.x, h = blockIdx.y, b = blockIdx.z;
  const int t = threadIdx.x;
  const int q = tile * 64 + t;
  const bool valid = q < MAXQ;
  const int qc = valid ? q : MAXQ - 1;
  float4* Qrow = (float4*)(QO + ((size_t)(b * MAXQ + qc)) * 256 + h * 32);
  const float4* Kb4 = (const float4*)(KV + (size_t)b * 256 * 512 + h * 32);

  float4 qv[8];
#pragma unroll
  for (int j = 0; j < 8; ++j) qv[j] = Qrow[j];

  float4 o[8];
#pragma unroll
  for (int j = 0; j < 8; ++j) o[j] = make_float4(0.f, 0.f, 0.f, 0.f);
  float m = -3.0e38f, z = 0.0f;

  float4 ka[8], va[8], kb[8], vb[8];
  LOADKV(ka, va, 0);
  for (int a2 = 0; a2 < 128; ++a2) {
    const int a = a2 * 2;
    LOADKV(kb, vb, a + 1);
    ASTEP(ka, va);
    if (a2 < 127) { LOADKV(ka, va, a + 2); }
    ASTEP(kb, vb);
  }

  if (valid) {
    float zi = 1.0f / z;
#pragma unroll
    for (int j = 0; j < 8; ++j) {
      float4 v;
      v.x = o[j].x * zi; v.y = o[j].y * zi;
      v.z = o[j].z * zi; v.w = o[j].w * zi;
      Qrow[j] = v;
    }
  }
}

// ---------------------------------------------------------------------------
extern "C" void kernel_launch(void* const* d_in, const int* in_sizes, int n_in,
                              void* d_out, int out_size, void* d_ws, size_t ws_size,
                              hipStream_t stream) {
  const float* density = (const float*)d_in[0];
  const float* pcount  = (const float*)d_in[1];
  const float* mem     = (const float*)d_in[2];
  const float* af      = (const float*)d_in[3];
  const float* pw1     = (const float*)d_in[4];
  const float* pb1     = (const float*)d_in[5];
  const float* pw2     = (const float*)d_in[6];
  const float* pb2     = (const float*)d_in[7];
  const float* inw     = (const float*)d_in[8];
  const float* inb     = (const float*)d_in[9];
  const float* outw    = (const float*)d_in[10];
  const float* outb    = (const float*)d_in[11];
  const float* qw      = (const float*)d_in[12];
  const float* qb      = (const float*)d_in[13];

  float* out = (float*)d_out;
  float* ws = (float*)d_ws;

  // ws layout (floats)
  float* positions  = ws;                          // 25,600 (pad 32,768)
  float* lgtab      = ws + 32768;                  // 102,400 (pad to 139,264)
  float* sampled    = ws + 139264;                 // 3,276,800
  float* Qbuf       = sampled + 3276800;           // 3,276,800 (Q, then content)
  float* agent_init = Qbuf + 3276800;              // 1,048,576
  float* KV         = agent_init + 1048576;        // 2,097,152  [4096][512]
  int*   nq_i       = (int*)(KV + 2097152);        // 16

  float* out_queries = out;                        // 3,276,800
  float* out_qpos    = out + 3276800;              // 3,276,800
  float* out_nq      = out + 6553600;              // 16
  float* out_mask    = out + 6553616;              // 12,800

  prep_kernel<<<(NB * HWD + 255) / 256, 256, 0, stream>>>(pcount, nq_i, out_nq, density, lgtab);
  sample_kernel<<<BQ, 256, 0, stream>>>(lgtab, nq_i, positions, out_mask);
  posmlp_kernel<<<BQ / 16, 256, 0, stream>>>(positions, pw1, pb1, pw2, pb2, out_qpos);
  bilinear_kernel<<<BQ, 64, 0, stream>>>(mem, positions, sampled);
  agent_init_kernel<<<4096 / 32, 256, 0, stream>>>(af, qw, qb, agent_init);
  // Q = sampled @ Wq^T + bq
  gemm_kernel<<<dim3(BQ / 64, 4), 256, 0, stream>>>(sampled, 256, inw, inb, nullptr, Qbuf, 256);
  // K|V = agent_init @ [Wk;Wv]^T + [bk;bv]  -> [4096][512]
  gemm_kernel<<<dim3(4096 / 64, 8), 256, 0, stream>>>(agent_init, 256, inw + 256 * 256, inb + 256, nullptr, KV, 512);
  // content (in-place over Qbuf)
  attn_kernel<<<dim3(13, 8, NB), 64, 0, stream>>>(Qbuf, KV);
  // queries = content @ out_w^T + out_b + query_pos
  gemm_kernel<<<dim3(BQ / 64, 4), 256, 0, stream>>>(Qbuf, 256, outw, outb, out_qpos, out_queries, 256);
}

// Round 5
// 721.514 us; speedup vs baseline: 1.7197x; 1.0169x over previous
//
#include <hip/hip_runtime.h>
#include <stdint.h>
#include <math.h>

#define NB 16
#define HD_ 80
#define WD_ 80
#define HWD 6400
#define MAXQ 800
#define EMB 256
#define NMEM 8400
#define BQ (NB*MAXQ)          // 12800

// ---------------------------------------------------------------------------
// Threefry2x32 with key (0, 42) — bit-exact with jax.random.key(42),
// partitionable scheme: bits(f) = o0 ^ o1, x0 = hi32(f) = 0 (f < 2^32 here).
__device__ __forceinline__ void tf2x32(uint32_t x0, uint32_t x1,
                                       uint32_t& o0, uint32_t& o1) {
  const uint32_t ks0 = 0u;
  const uint32_t ks1 = 42u;
  const uint32_t ks2 = 0x1BD11BDAu ^ 0u ^ 42u;
  x0 += ks0; x1 += ks1;
#define TF_ROT(r) { x0 += x1; x1 = (x1 << (r)) | (x1 >> (32 - (r))); x1 ^= x0; }
  TF_ROT(13) TF_ROT(15) TF_ROT(26) TF_ROT(6)
  x0 += ks1; x1 += ks2 + 1u;
  TF_ROT(17) TF_ROT(29) TF_ROT(16) TF_ROT(24)
  x0 += ks2; x1 += ks0 + 2u;
  TF_ROT(13) TF_ROT(15) TF_ROT(26) TF_ROT(6)
  x0 += ks0; x1 += ks1 + 3u;
  TF_ROT(17) TF_ROT(29) TF_ROT(16) TF_ROT(24)
  x0 += ks1; x1 += ks2 + 4u;
  TF_ROT(13) TF_ROT(15) TF_ROT(26) TF_ROT(6)
  x0 += ks2; x1 += ks0 + 5u;
#undef TF_ROT
  o0 = x0; o1 = x1;
}

// ---------------------------------------------------------------------------
// prep: nq (+float copy out) and lg table = density / 0.1 (hoisted divide)
__global__ __launch_bounds__(256)
void prep_kernel(const float* __restrict__ pc, int* __restrict__ nq_i,
                 float* __restrict__ out_nq,
                 const float* __restrict__ density, float* __restrict__ lgtab) {
  int i = blockIdx.x * 256 + threadIdx.x;
  if (i < NB * HWD) lgtab[i] = density[i] / 0.1f;
  if (i < NB) {
    float v = floorf(pc[i] * 2.0f);
    int n = (int)v;
    n = n < 100 ? 100 : (n > 800 ? 800 : n);
    nq_i[i] = n;
    out_nq[i] = (float)n;
  }
}

// ---------------------------------------------------------------------------
// Gumbel-max categorical sampling. One block per (b,q); argmax over 6400.
// Gumbel computed with 2 hardware v_log_f32:
//   u = bits-to-[0,1);  e = -ln(u) = -ln2*log2(u);  g+lg = lg - ln2*log2(e)
// u==0 -> log2(u)=-inf -> e=+inf -> val=-inf (never selected; matches ref
// where the tiny-clamped candidate also never wins the argmax).
__global__ __launch_bounds__(256)
void sample_kernel(const float* __restrict__ lgs, const int* __restrict__ nq_i,
                   float* __restrict__ positions, float* __restrict__ mask_out) {
  __shared__ float swv[4];
  __shared__ int   swi[4];
  const int bq = blockIdx.x;
  const int b = bq / MAXQ;
  const int q = bq - b * MAXQ;
  const int t = threadIdx.x;
  const float* lg = lgs + b * HWD;
  const uint32_t base = (uint32_t)bq * (uint32_t)HWD;  // < 2^32

  const float NLN2 = -0.69314718055994530942f;
  float best = -3.0e38f;
  int besti = HWD;
#pragma unroll 5
  for (int i = 0; i < 25; ++i) {
    int c = t + (i << 8);
    uint32_t o0, o1;
    tf2x32(0u, base + (uint32_t)c, o0, o1);
    uint32_t bits = o0 ^ o1;
    float u = __uint_as_float((bits >> 9) | 0x3f800000u) - 1.0f;
    float l2;
    asm("v_log_f32 %0, %1" : "=v"(l2) : "v"(u));   // log2(u) <= 0
    float e = NLN2 * l2;                           // -ln(u) >= 0
    float l3;
    asm("v_log_f32 %0, %1" : "=v"(l3) : "v"(e));   // log2(e)
    float val = fmaf(NLN2, l3, lg[c]);             // g + lg
    if (val > best) { best = val; besti = c; }     // per-thread c ascending
  }
  // wave-level argmax (value desc, index asc on ties)
#pragma unroll
  for (int off = 32; off; off >>= 1) {
    float ov = __shfl_xor(best, off);
    int   oi = __shfl_xor(besti, off);
    if (ov > best || (ov == best && oi < besti)) { best = ov; besti = oi; }
  }
  if ((t & 63) == 0) { swv[t >> 6] = best; swi[t >> 6] = besti; }
  __syncthreads();
  if (t == 0) {
    float bv = swv[0]; int bi = swi[0];
#pragma unroll
    for (int w = 1; w < 4; ++w) {
      float ov = swv[w]; int oi = swi[w];
      if (ov > bv || (ov == bv && oi < bi)) { bv = ov; bi = oi; }
    }
    int n = nq_i[b];
    float px, py;
    if (q >= n) { px = 0.0f; py = 0.0f; }
    else {
      py = (float)(bi / WD_) / 80.0f;
      px = (float)(bi % WD_) / 80.0f;
    }
    positions[2 * bq]     = px;
    positions[2 * bq + 1] = py;
    mask_out[bq] = (q >= n) ? 1.0f : 0.0f;
  }
}

// ---------------------------------------------------------------------------
__device__ __forceinline__ float gelu_tanh(float x) {
  float x3 = x * x * x;
  float inner = 0.7978845608028654f * (x + 0.044715f * x3);
  float cdf = 0.5f * (1.0f + tanhf(inner));
  return x * cdf;
}

__global__ __launch_bounds__(256)
void posmlp_kernel(const float* __restrict__ positions,
                   const float* __restrict__ w1, const float* __restrict__ b1,
                   const float* __restrict__ w2, const float* __restrict__ b2,
                   float* __restrict__ qpos) {
  __shared__ float ppos[16][2];
  __shared__ float h_all[16 * 128];
  const int t = threadIdx.x;
  const size_t q0 = (size_t)blockIdx.x * 16;
  if (t < 32) ppos[t >> 1][t & 1] = positions[q0 * 2 + t];
  __syncthreads();
  for (int j = t; j < 2048; j += 256) {
    int qi = j >> 7, k = j & 127;
    float x = ppos[qi][0] * w1[k] + ppos[qi][1] * w1[128 + k] + b1[k];
    h_all[j] = gelu_tanh(x);
  }
  __syncthreads();
  float acc[16];
#pragma unroll
  for (int qi = 0; qi < 16; ++qi) acc[qi] = 0.0f;
  for (int k = 0; k < 128; ++k) {
    float wv = w2[k * 256 + t];
#pragma unroll
    for (int qi = 0; qi < 16; ++qi) acc[qi] += h_all[qi * 128 + k] * wv;
  }
  float bv = b2[t];
#pragma unroll
  for (int qi = 0; qi < 16; ++qi)
    qpos[(q0 + qi) * 256 + t] = acc[qi] + bv;
}

// ---------------------------------------------------------------------------
// Bilinear grid_sample, float4-vectorized: 64 threads per query, 4 channels
// per thread. FP weight chain replicated exactly from the reference.
__global__ __launch_bounds__(64)
void bilinear_kernel(const float* __restrict__ mem,
                     const float* __restrict__ positions,
                     float* __restrict__ sampled) {
  const int bq = blockIdx.x;
  const int b = bq / MAXQ;
  const int t = threadIdx.x;                 // float4 channel group 0..63
  float px = positions[2 * bq], py = positions[2 * bq + 1];
  float gx = px * 2.0f - 1.0f;
  float gy = py * 2.0f - 1.0f;
  float x = (gx + 1.0f) * 0.5f * 80.0f - 0.5f;
  float y = (gy + 1.0f) * 0.5f * 80.0f - 0.5f;
  float x0f = floorf(x), y0f = floorf(y);
  float wx1 = x - x0f, wx0 = 1.0f - wx1;
  float wy1 = y - y0f, wy0 = 1.0f - wy1;
  int x0 = (int)x0f, y0 = (int)y0f;
  int x1 = x0 + 1, y1 = y0 + 1;
  const float4* fmb = (const float4*)(mem + (size_t)b * NMEM * EMB);
  float4 acc = make_float4(0.f, 0.f, 0.f, 0.f);
#define BIL_CORNER(yy, xx, wt) \
  if ((yy) >= 0 && (yy) < HD_ && (xx) >= 0 && (xx) < WD_) {            \
    float4 v = fmb[(size_t)((yy) * WD_ + (xx)) * 64 + t];              \
    acc.x += (wt) * v.x; acc.y += (wt) * v.y;                          \
    acc.z += (wt) * v.z; acc.w += (wt) * v.w; }
  BIL_CORNER(y0, x0, wy0 * wx0)
  BIL_CORNER(y0, x1, wy0 * wx1)
  BIL_CORNER(y1, x0, wy1 * wx0)
  BIL_CORNER(y1, x1, wy1 * wx1)
#undef BIL_CORNER
  ((float4*)sampled)[(size_t)bq * 64 + t] = acc;
}

// ---------------------------------------------------------------------------
__global__ __launch_bounds__(256)
void agent_init_kernel(const float* __restrict__ af, const float* __restrict__ qw,
                       const float* __restrict__ qb, float* __restrict__ out) {
  __shared__ float xs[32 * 64];
  const int t = threadIdx.x;
  const size_t r0 = (size_t)blockIdx.x * 32;
  for (int j = t; j < 32 * 64; j += 256) xs[j] = af[r0 * 64 + j];
  __syncthreads();
  float acc[32];
#pragma unroll
  for (int r = 0; r < 32; ++r) acc[r] = 0.0f;
  for (int k = 0; k < 64; ++k) {
    float wv = qw[k * 256 + t];
#pragma unroll
    for (int r = 0; r < 32; ++r) acc[r] += xs[r * 64 + k] * wv;
  }
  float bv = qb[t];
#pragma unroll
  for (int r = 0; r < 32; ++r)
    out[(r0 + r) * 256 + t] = acc[r] + bv;
}

// ---------------------------------------------------------------------------
// Register-tiled fp32 GEMM: out[r][c] = sum_k X[r][k]*W[c][k] + bias[c]
// (+ add). ldx/ldc generalize input/output row strides (K fixed at 256).
__global__ __launch_bounds__(256)
void gemm_kernel(const float* __restrict__ X, int ldx,
                 const float* __restrict__ W,
                 const float* __restrict__ bias, const float* __restrict__ add,
                 float* __restrict__ out, int ldc) {
  __shared__ float Xs[64 * 36];
  __shared__ float Ws[64 * 36];
  const int t = threadIdx.x;
  const int tc = t & 15, tr = t >> 4;
  const size_t row0 = (size_t)blockIdx.x * 64;
  const int col0 = blockIdx.y * 64;
  float acc[4][4] = {};
  for (int kt = 0; kt < 8; ++kt) {
    __syncthreads();
#pragma unroll
    for (int p = 0; p < 2; ++p) {
      int j4 = t + p * 256;              // 0..511
      int r = j4 >> 3, kq = j4 & 7;
      float4 xv = *(const float4*)&X[(row0 + r) * ldx + kt * 32 + kq * 4];
      *(float4*)&Xs[r * 36 + kq * 4] = xv;
      float4 wv = *(const float4*)&W[(size_t)(col0 + r) * 256 + kt * 32 + kq * 4];
      *(float4*)&Ws[r * 36 + ((kq * 4) ^ (4 * ((r >> 2) & 7)))] = wv;
    }
    __syncthreads();
#pragma unroll
    for (int kq = 0; kq < 8; ++kq) {
      float4 xv[4], wv[4];
#pragma unroll
      for (int i = 0; i < 4; ++i)
        xv[i] = *(const float4*)&Xs[(tr * 4 + i) * 36 + kq * 4];
#pragma unroll
      for (int j = 0; j < 4; ++j)
        wv[j] = *(const float4*)&Ws[(tc * 4 + j) * 36 + ((kq * 4) ^ (4 * (tc & 7)))];
#pragma unroll
      for (int i = 0; i < 4; ++i)
#pragma unroll
        for (int j = 0; j < 4; ++j)
          acc[i][j] += xv[i].x * wv[j].x + xv[i].y * wv[j].y
                     + xv[i].z * wv[j].z + xv[i].w * wv[j].w;
    }
  }
  float4 bv = *(const float4*)&bias[col0 + tc * 4];
#pragma unroll
  for (int i = 0; i < 4; ++i) {
    size_t row = row0 + tr * 4 + i;
    float4 v;
    v.x = acc[i][0] + bv.x; v.y = acc[i][1] + bv.y;
    v.z = acc[i][2] + bv.z; v.w = acc[i][3] + bv.w;
    if (add) {
      float4 av = *(const float4*)&add[row * 256 + col0 + tc * 4];
      v.x += av.x; v.y += av.y; v.z += av.z; v.w += av.w;
    }
    *(float4*)&out[row * ldc + col0 + tc * 4] = v;
  }
}

// ---------------------------------------------------------------------------
// Cross-attention v3: LDS-staged K/V, one query per thread, 128-thread
// blocks (2 waves), grid (7 qtiles, 8 heads, 16 b) = 896 blocks (~7 waves/CU).
// K/V staged per 64-agent chunk (16 KB LDS), coalesced float4 loads; compute
// reads are wave-uniform LDS broadcasts (conflict-free). In-place O over Q.
#define ASTEP(kk, vv) {                                            \
  float s0 = 0.f, s1 = 0.f, s2 = 0.f, s3 = 0.f;                    \
  _Pragma("unroll") for (int j = 0; j < 8; ++j) {                  \
    s0 += qv[j].x * kk[j].x; s1 += qv[j].y * kk[j].y;              \
    s2 += qv[j].z * kk[j].z; s3 += qv[j].w * kk[j].w; }            \
  float s = ((s0 + s1) + (s2 + s3)) * 0.17677669529663689f;        \
  if (s > m + 8.0f) {                                              \
    float r = expf(m - s);                                         \
    z = z * r + 1.0f;                                              \
    _Pragma("unroll") for (int j = 0; j < 8; ++j) {                \
      o[j].x = o[j].x * r + vv[j].x; o[j].y = o[j].y * r + vv[j].y;\
      o[j].z = o[j].z * r + vv[j].z; o[j].w = o[j].w * r + vv[j].w; } \
    m = s;                                                         \
  } else {                                                         \
    float p = expf(s - m);                                         \
    z += p;                                                        \
    _Pragma("unroll") for (int j = 0; j < 8; ++j) {                \
      o[j].x += p * vv[j].x; o[j].y += p * vv[j].y;                \
      o[j].z += p * vv[j].z; o[j].w += p * vv[j].w; } } }

__global__ __launch_bounds__(128)
void attn_kernel(float* __restrict__ QO, const float* __restrict__ KV) {
  __shared__ float Ks[64 * 32];
  __shared__ float Vs[64 * 32];
  const int tile = blockIdx.x, h = blockIdx.y, b = blockIdx.z;
  const int t = threadIdx.x;
  const int q = tile * 128 + t;
  const bool valid = q < MAXQ;
  const int qc = valid ? q : MAXQ - 1;
  float4* Qrow = (float4*)(QO + ((size_t)(b * MAXQ + qc)) * 256 + h * 32);
  // KV in float4 units: row stride 128; K at f4col h*8, V at 64 + h*8
  const float4* KVb4 = (const float4*)KV + (size_t)b * 256 * 128 + h * 8;

  float4 qv[8];
#pragma unroll
  for (int j = 0; j < 8; ++j) qv[j] = Qrow[j];

  float4 o[8];
#pragma unroll
  for (int j = 0; j < 8; ++j) o[j] = make_float4(0.f, 0.f, 0.f, 0.f);
  float m = -3.0e38f, z = 0.0f;

  for (int ch = 0; ch < 4; ++ch) {
    __syncthreads();   // previous chunk fully consumed before overwrite
    // stage chunk: 64 agents x (8 K-float4 + 8 V-float4) = 1024 f4, 8/thread
#pragma unroll
    for (int r = 0; r < 8; ++r) {
      int flat = t + 128 * r;            // 0..1023
      int isv  = flat >> 9;              // 0: K, 1: V
      int idx  = flat & 511;
      int row  = idx >> 3, fc = idx & 7;
      float4 val = KVb4[(size_t)(ch * 64 + row) * 128 + isv * 64 + fc];
      if (isv == 0) ((float4*)Ks)[row * 8 + fc] = val;
      else          ((float4*)Vs)[row * 8 + fc] = val;
    }
    __syncthreads();
#pragma unroll 2
    for (int a = 0; a < 64; ++a) {
      const float4* kr = (const float4*)&Ks[a * 32];
      const float4* vr = (const float4*)&Vs[a * 32];
      ASTEP(kr, vr);
    }
  }

  if (valid) {
    float zi = 1.0f / z;
#pragma unroll
    for (int j = 0; j < 8; ++j) {
      float4 v;
      v.x = o[j].x * zi; v.y = o[j].y * zi;
      v.z = o[j].z * zi; v.w = o[j].w * zi;
      Qrow[j] = v;
    }
  }
}

// ---------------------------------------------------------------------------
extern "C" void kernel_launch(void* const* d_in, const int* in_sizes, int n_in,
                              void* d_out, int out_size, void* d_ws, size_t ws_size,
                              hipStream_t stream) {
  const float* density = (const float*)d_in[0];
  const float* pcount  = (const float*)d_in[1];
  const float* mem     = (const float*)d_in[2];
  const float* af      = (const float*)d_in[3];
  const float* pw1     = (const float*)d_in[4];
  const float* pb1     = (const float*)d_in[5];
  const float* pw2     = (const float*)d_in[6];
  const float* pb2     = (const float*)d_in[7];
  const float* inw     = (const float*)d_in[8];
  const float* inb     = (const float*)d_in[9];
  const float* outw    = (const float*)d_in[10];
  const float* outb    = (const float*)d_in[11];
  const float* qw      = (const float*)d_in[12];
  const float* qb      = (const float*)d_in[13];

  float* out = (float*)d_out;
  float* ws = (float*)d_ws;

  // ws layout (floats)
  float* positions  = ws;                          // 25,600 (pad 32,768)
  float* lgtab      = ws + 32768;                  // 102,400 (pad to 139,264)
  float* sampled    = ws + 139264;                 // 3,276,800
  float* Qbuf       = sampled + 3276800;           // 3,276,800 (Q, then content)
  float* agent_init = Qbuf + 3276800;              // 1,048,576
  float* KV         = agent_init + 1048576;        // 2,097,152  [4096][512]
  int*   nq_i       = (int*)(KV + 2097152);        // 16

  float* out_queries = out;                        // 3,276,800
  float* out_qpos    = out + 3276800;              // 3,276,800
  float* out_nq      = out + 6553600;              // 16
  float* out_mask    = out + 6553616;              // 12,800

  prep_kernel<<<(NB * HWD + 255) / 256, 256, 0, stream>>>(pcount, nq_i, out_nq, density, lgtab);
  sample_kernel<<<BQ, 256, 0, stream>>>(lgtab, nq_i, positions, out_mask);
  posmlp_kernel<<<BQ / 16, 256, 0, stream>>>(positions, pw1, pb1, pw2, pb2, out_qpos);
  bilinear_kernel<<<BQ, 64, 0, stream>>>(mem, positions, sampled);
  agent_init_kernel<<<4096 / 32, 256, 0, stream>>>(af, qw, qb, agent_init);
  // Q = sampled @ Wq^T + bq
  gemm_kernel<<<dim3(BQ / 64, 4), 256, 0, stream>>>(sampled, 256, inw, inb, nullptr, Qbuf, 256);
  // K|V = agent_init @ [Wk;Wv]^T + [bk;bv]  -> [4096][512]
  gemm_kernel<<<dim3(4096 / 64, 8), 256, 0, stream>>>(agent_init, 256, inw + 256 * 256, inb + 256, nullptr, KV, 512);
  // content (in-place over Qbuf)
  attn_kernel<<<dim3(7, 8, NB), 128, 0, stream>>>(Qbuf, KV);
  // queries = content @ out_w^T + out_b + query_pos
  gemm_kernel<<<dim3(BQ / 64, 4), 256, 0, stream>>>(Qbuf, 256, outw, outb, out_qpos, out_queries, 256);
}

// Round 7
// 672.678 us; speedup vs baseline: 1.8446x; 1.0726x over previous
//
#include <hip/hip_runtime.h>
#include <stdint.h>
#include <math.h>

#define NB 16
#define HD_ 80
#define WD_ 80
#define HWD 6400
#define MAXQ 800
#define EMB 256
#define NMEM 8400
#define BQ (NB*MAXQ)          // 12800

typedef __attribute__((ext_vector_type(8))) short bf16x8;
typedef __attribute__((ext_vector_type(4))) float f32x4;

__device__ __forceinline__ ushort f2bf(float f) {
  uint32_t u = __float_as_uint(f);
  uint32_t r = (u + 0x7FFFu + ((u >> 16) & 1u)) >> 16;
  return (ushort)r;
}

// ---------------------------------------------------------------------------
// Threefry2x32 with key (0, 42) — bit-exact with jax.random.key(42),
// partitionable scheme: bits(f) = o0 ^ o1, x0 = hi32(f) = 0 (f < 2^32 here).
__device__ __forceinline__ void tf2x32(uint32_t x0, uint32_t x1,
                                       uint32_t& o0, uint32_t& o1) {
  const uint32_t ks0 = 0u;
  const uint32_t ks1 = 42u;
  const uint32_t ks2 = 0x1BD11BDAu ^ 0u ^ 42u;
  x0 += ks0; x1 += ks1;
#define TF_ROT(r) { x0 += x1; x1 = (x1 << (r)) | (x1 >> (32 - (r))); x1 ^= x0; }
  TF_ROT(13) TF_ROT(15) TF_ROT(26) TF_ROT(6)
  x0 += ks1; x1 += ks2 + 1u;
  TF_ROT(17) TF_ROT(29) TF_ROT(16) TF_ROT(24)
  x0 += ks2; x1 += ks0 + 2u;
  TF_ROT(13) TF_ROT(15) TF_ROT(26) TF_ROT(6)
  x0 += ks0; x1 += ks1 + 3u;
  TF_ROT(17) TF_ROT(29) TF_ROT(16) TF_ROT(24)
  x0 += ks1; x1 += ks2 + 4u;
  TF_ROT(13) TF_ROT(15) TF_ROT(26) TF_ROT(6)
  x0 += ks2; x1 += ks0 + 5u;
#undef TF_ROT
  o0 = x0; o1 = x1;
}

// ---------------------------------------------------------------------------
// prep: nq, lgtab = density/0.1, and all fp32->bf16 weight/activation
// conversions (inw rows 0..767, outw, qw transposed, af).
__global__ __launch_bounds__(256)
void prep_kernel(const float* __restrict__ pc, int* __restrict__ nq_i,
                 float* __restrict__ out_nq,
                 const float* __restrict__ density, float* __restrict__ lgtab,
                 const float* __restrict__ inw, const float* __restrict__ outw,
                 const float* __restrict__ qw, const float* __restrict__ af,
                 ushort* __restrict__ inwB, ushort* __restrict__ outwB,
                 ushort* __restrict__ qwtB, ushort* __restrict__ afB) {
  int i = blockIdx.x * 256 + threadIdx.x;
  if (i < NB * HWD) lgtab[i] = density[i] / 0.1f;
  if (i < NB) {
    float v = floorf(pc[i] * 2.0f);
    int n = (int)v;
    n = n < 100 ? 100 : (n > 800 ? 800 : n);
    nq_i[i] = n;
    out_nq[i] = (float)n;
  }
  // conversion ranges (total 540,672)
  if (i < 196608) {
    inwB[i] = f2bf(inw[i]);
  } else if (i < 196608 + 65536) {
    int j = i - 196608;
    outwB[j] = f2bf(outw[j]);
  } else if (i < 196608 + 65536 + 16384) {
    int j = i - (196608 + 65536);
    int c = j >> 6, k = j & 63;           // qwtB[c][k] = qw[k][c]
    qwtB[j] = f2bf(qw[k * 256 + c]);
  } else if (i < 196608 + 65536 + 16384 + 262144) {
    int j = i - (196608 + 65536 + 16384);
    afB[j] = f2bf(af[j]);
  }
}

// ---------------------------------------------------------------------------
// Gumbel-max categorical sampling (unchanged; at its threefry VALU floor).
__global__ __launch_bounds__(256)
void sample_kernel(const float* __restrict__ lgs, const int* __restrict__ nq_i,
                   float* __restrict__ positions, float* __restrict__ mask_out) {
  __shared__ float swv[4];
  __shared__ int   swi[4];
  const int bq = blockIdx.x;
  const int b = bq / MAXQ;
  const int q = bq - b * MAXQ;
  const int t = threadIdx.x;
  const float* lg = lgs + b * HWD;
  const uint32_t base = (uint32_t)bq * (uint32_t)HWD;  // < 2^32

  const float NLN2 = -0.69314718055994530942f;
  float best = -3.0e38f;
  int besti = HWD;
#pragma unroll 5
  for (int i = 0; i < 25; ++i) {
    int c = t + (i << 8);
    uint32_t o0, o1;
    tf2x32(0u, base + (uint32_t)c, o0, o1);
    uint32_t bits = o0 ^ o1;
    float u = __uint_as_float((bits >> 9) | 0x3f800000u) - 1.0f;
    float l2;
    asm("v_log_f32 %0, %1" : "=v"(l2) : "v"(u));   // log2(u) <= 0
    float e = NLN2 * l2;                           // -ln(u) >= 0
    float l3;
    asm("v_log_f32 %0, %1" : "=v"(l3) : "v"(e));   // log2(e)
    float val = fmaf(NLN2, l3, lg[c]);             // g + lg
    if (val > best) { best = val; besti = c; }     // per-thread c ascending
  }
#pragma unroll
  for (int off = 32; off; off >>= 1) {
    float ov = __shfl_xor(best, off);
    int   oi = __shfl_xor(besti, off);
    if (ov > best || (ov == best && oi < besti)) { best = ov; besti = oi; }
  }
  if ((t & 63) == 0) { swv[t >> 6] = best; swi[t >> 6] = besti; }
  __syncthreads();
  if (t == 0) {
    float bv = swv[0]; int bi = swi[0];
#pragma unroll
    for (int w = 1; w < 4; ++w) {
      float ov = swv[w]; int oi = swi[w];
      if (ov > bv || (ov == bv && oi < bi)) { bv = ov; bi = oi; }
    }
    int n = nq_i[b];
    float px, py;
    if (q >= n) { px = 0.0f; py = 0.0f; }
    else {
      py = (float)(bi / WD_) / 80.0f;
      px = (float)(bi % WD_) / 80.0f;
    }
    positions[2 * bq]     = px;
    positions[2 * bq + 1] = py;
    mask_out[bq] = (q >= n) ? 1.0f : 0.0f;
  }
}

// ---------------------------------------------------------------------------
__device__ __forceinline__ float gelu_tanh(float x) {
  float x3 = x * x * x;
  float inner = 0.7978845608028654f * (x + 0.044715f * x3);
  float cdf = 0.5f * (1.0f + tanhf(inner));
  return x * cdf;
}

// posmlp stays fp32 (output 1 precision). Inner loop float4 LDS reads.
__global__ __launch_bounds__(256)
void posmlp_kernel(const float* __restrict__ positions,
                   const float* __restrict__ w1, const float* __restrict__ b1,
                   const float* __restrict__ w2, const float* __restrict__ b2,
                   float* __restrict__ qpos) {
  __shared__ float ppos[16][2];
  __shared__ float h_all[16 * 128];
  const int t = threadIdx.x;
  const size_t q0 = (size_t)blockIdx.x * 16;
  if (t < 32) ppos[t >> 1][t & 1] = positions[q0 * 2 + t];
  __syncthreads();
  for (int j = t; j < 2048; j += 256) {
    int qi = j >> 7, k = j & 127;
    float x = ppos[qi][0] * w1[k] + ppos[qi][1] * w1[128 + k] + b1[k];
    h_all[j] = gelu_tanh(x);
  }
  __syncthreads();
  float acc[16];
#pragma unroll
  for (int qi = 0; qi < 16; ++qi) acc[qi] = 0.0f;
  for (int k4 = 0; k4 < 32; ++k4) {
    float wv0 = w2[(k4 * 4 + 0) * 256 + t];
    float wv1 = w2[(k4 * 4 + 1) * 256 + t];
    float wv2 = w2[(k4 * 4 + 2) * 256 + t];
    float wv3 = w2[(k4 * 4 + 3) * 256 + t];
#pragma unroll
    for (int qi = 0; qi < 16; ++qi) {
      float4 h4 = *(const float4*)&h_all[qi * 128 + k4 * 4];
      acc[qi] = fmaf(h4.x, wv0, fmaf(h4.y, wv1, fmaf(h4.z, wv2, fmaf(h4.w, wv3, acc[qi]))));
    }
  }
  float bv = b2[t];
#pragma unroll
  for (int qi = 0; qi < 16; ++qi)
    qpos[(q0 + qi) * 256 + t] = acc[qi] + bv;
}

// ---------------------------------------------------------------------------
// Bilinear grid_sample; fp32 weight chain exact; emits bf16 (feeds Q-GEMM).
__global__ __launch_bounds__(64)
void bilinear_kernel(const float* __restrict__ mem,
                     const float* __restrict__ positions,
                     ushort* __restrict__ sampledB) {
  const int bq = blockIdx.x;
  const int b = bq / MAXQ;
  const int t = threadIdx.x;                 // float4 channel group 0..63
  float px = positions[2 * bq], py = positions[2 * bq + 1];
  float gx = px * 2.0f - 1.0f;
  float gy = py * 2.0f - 1.0f;
  float x = (gx + 1.0f) * 0.5f * 80.0f - 0.5f;
  float y = (gy + 1.0f) * 0.5f * 80.0f - 0.5f;
  float x0f = floorf(x), y0f = floorf(y);
  float wx1 = x - x0f, wx0 = 1.0f - wx1;
  float wy1 = y - y0f, wy0 = 1.0f - wy1;
  int x0 = (int)x0f, y0 = (int)y0f;
  int x1 = x0 + 1, y1 = y0 + 1;
  const float4* fmb = (const float4*)(mem + (size_t)b * NMEM * EMB);
  float4 acc = make_float4(0.f, 0.f, 0.f, 0.f);
#define BIL_CORNER(yy, xx, wt) \
  if ((yy) >= 0 && (yy) < HD_ && (xx) >= 0 && (xx) < WD_) {            \
    float4 v = fmb[(size_t)((yy) * WD_ + (xx)) * 64 + t];              \
    acc.x += (wt) * v.x; acc.y += (wt) * v.y;                          \
    acc.z += (wt) * v.z; acc.w += (wt) * v.w; }
  BIL_CORNER(y0, x0, wy0 * wx0)
  BIL_CORNER(y0, x1, wy0 * wx1)
  BIL_CORNER(y1, x0, wy1 * wx0)
  BIL_CORNER(y1, x1, wy1 * wx1)
#undef BIL_CORNER
  ushort4 s;
  s.x = f2bf(acc.x); s.y = f2bf(acc.y); s.z = f2bf(acc.z); s.w = f2bf(acc.w);
  ((ushort4*)sampledB)[(size_t)bq * 64 + t] = s;
}

// ---------------------------------------------------------------------------
// MFMA bf16 GEMM: out[r][c] = sum_k X[r][k]*W[c][k] + bias[c] (+ add).
// Tile 64x64, 4 waves (2x2), MFMA 16x16x32, K param (multiple of 32).
// Operand layout (m89-verified): A row=lane&15, k=8*(lane>>4)+j; B same on
// W[c][k]; D col=lane&15, row=4*(lane>>4)+reg.
template<int OUTBF16>
__global__ __launch_bounds__(256)
void mfma_gemm(const ushort* __restrict__ X, int ldx,
               const ushort* __restrict__ W, int K,
               const float* __restrict__ bias, const float* __restrict__ add,
               void* __restrict__ out, int ldc) {
  __shared__ ushort Xs[64 * 32];
  __shared__ ushort Ws[64 * 32];
  const int t = threadIdx.x;
  const size_t row0 = (size_t)blockIdx.x * 64;
  const int col0 = blockIdx.y * 64;
  const int w = t >> 6, lane = t & 63;
  const int wm = w >> 1, wn = w & 1;
  const int lr = lane & 15, lg = lane >> 4;
  const int swl = (lg ^ (lr & 3)) * 8;       // swizzled granule offset
  const int srow = t >> 2, sg = t & 3;       // staging: row, granule
  const int sdst = srow * 32 + ((sg ^ (srow & 3)) * 8);

  f32x4 acc[2][2];
#pragma unroll
  for (int mi = 0; mi < 2; ++mi)
#pragma unroll
    for (int ni = 0; ni < 2; ++ni) acc[mi][ni] = 0.0f;

  const int nk = K >> 5;
  for (int kt = 0; kt < nk; ++kt) {
    const int k0 = kt * 32;
    uint4 xv = *(const uint4*)(X + (row0 + srow) * ldx + k0 + sg * 8);
    uint4 wv = *(const uint4*)(W + (size_t)(col0 + srow) * K + k0 + sg * 8);
    *(uint4*)&Xs[sdst] = xv;
    *(uint4*)&Ws[sdst] = wv;
    __syncthreads();
    bf16x8 a[2], b[2];
#pragma unroll
    for (int mi = 0; mi < 2; ++mi)
      a[mi] = *(const bf16x8*)&Xs[(wm * 32 + mi * 16 + lr) * 32 + swl];
#pragma unroll
    for (int ni = 0; ni < 2; ++ni)
      b[ni] = *(const bf16x8*)&Ws[(wn * 32 + ni * 16 + lr) * 32 + swl];
#pragma unroll
    for (int mi = 0; mi < 2; ++mi)
#pragma unroll
      for (int ni = 0; ni < 2; ++ni)
        acc[mi][ni] = __builtin_amdgcn_mfma_f32_16x16x32_bf16(a[mi], b[ni], acc[mi][ni], 0, 0, 0);
    __syncthreads();
  }

#pragma unroll
  for (int mi = 0; mi < 2; ++mi)
#pragma unroll
    for (int ni = 0; ni < 2; ++ni) {
      const int gcol = col0 + wn * 32 + ni * 16 + lr;
      const float bv = bias[gcol];
#pragma unroll
      for (int rr = 0; rr < 4; ++rr) {
        const size_t grow = row0 + wm * 32 + mi * 16 + lg * 4 + rr;
        float v = acc[mi][ni][rr] + bv;
        if (add) v += add[grow * ldc + gcol];
        if (OUTBF16) ((ushort*)out)[grow * ldc + gcol] = f2bf(v);
        else         ((float*)out)[grow * ldc + gcol] = v;
      }
    }
}

// ---------------------------------------------------------------------------
// Cross-attention: LDS-staged K/V, 2 queries per thread (q, q+512),
// 128-thread blocks, grid (4, 8, 16). Emits bf16 content (feeds out-GEMM).
// NOTE: macro params are uppercase to avoid token-collision with .x/.y/.z/.w
#define ASTEP(QQ, KK, VV, MM, ZZ, OO) {                            \
  float s0 = 0.f, s1 = 0.f, s2 = 0.f, s3 = 0.f;                    \
  _Pragma("unroll") for (int j = 0; j < 8; ++j) {                  \
    s0 += QQ[j].x * KK[j].x; s1 += QQ[j].y * KK[j].y;              \
    s2 += QQ[j].z * KK[j].z; s3 += QQ[j].w * KK[j].w; }            \
  float s = ((s0 + s1) + (s2 + s3)) * 0.17677669529663689f;        \
  if (s > MM + 8.0f) {                                             \
    float r = expf(MM - s);                                        \
    ZZ = ZZ * r + 1.0f;                                            \
    _Pragma("unroll") for (int j = 0; j < 8; ++j) {                \
      OO[j].x = OO[j].x * r + VV[j].x; OO[j].y = OO[j].y * r + VV[j].y; \
      OO[j].z = OO[j].z * r + VV[j].z; OO[j].w = OO[j].w * r + VV[j].w; } \
    MM = s;                                                        \
  } else {                                                         \
    float p = expf(s - MM);                                        \
    ZZ += p;                                                       \
    _Pragma("unroll") for (int j = 0; j < 8; ++j) {                \
      OO[j].x += p * VV[j].x; OO[j].y += p * VV[j].y;              \
      OO[j].z += p * VV[j].z; OO[j].w += p * VV[j].w; } } }

__global__ __launch_bounds__(128)
void attn_kernel(const float* __restrict__ Q, const float* __restrict__ KV,
                 ushort* __restrict__ contentB) {
  __shared__ float Ks[64 * 32];
  __shared__ float Vs[64 * 32];
  const int tile = blockIdx.x, h = blockIdx.y, b = blockIdx.z;
  const int t = threadIdx.x;
  const int qA = tile * 128 + t;            // < 512, always valid
  const int qB = qA + 512;
  const bool vB = qB < MAXQ;
  const float4* QrowA = (const float4*)(Q + ((size_t)(b * MAXQ + qA)) * 256 + h * 32);
  const float4* QrowB = (const float4*)(Q + ((size_t)(b * MAXQ + (vB ? qB : 0))) * 256 + h * 32);
  const float4* KVb4 = (const float4*)KV + (size_t)b * 256 * 128 + h * 8;

  float4 qa[8], qb_[8];
#pragma unroll
  for (int j = 0; j < 8; ++j) { qa[j] = QrowA[j]; qb_[j] = QrowB[j]; }
  float4 oA[8], oB[8];
#pragma unroll
  for (int j = 0; j < 8; ++j) {
    oA[j] = make_float4(0.f, 0.f, 0.f, 0.f);
    oB[j] = make_float4(0.f, 0.f, 0.f, 0.f);
  }
  float mA = -3.0e38f, zA = 0.0f, mB = -3.0e38f, zB = 0.0f;

  for (int ch = 0; ch < 4; ++ch) {
    __syncthreads();
#pragma unroll
    for (int r = 0; r < 8; ++r) {
      int flat = t + 128 * r;            // 0..1023
      int isv  = flat >> 9;              // 0: K, 1: V
      int idx  = flat & 511;
      int row  = idx >> 3, fc = idx & 7;
      float4 val = KVb4[(size_t)(ch * 64 + row) * 128 + isv * 64 + fc];
      if (isv == 0) ((float4*)Ks)[row * 8 + fc] = val;
      else          ((float4*)Vs)[row * 8 + fc] = val;
    }
    __syncthreads();
    for (int a = 0; a < 64; ++a) {
      float4 kk[8], vv[8];
#pragma unroll
      for (int j = 0; j < 8; ++j) {
        kk[j] = ((const float4*)&Ks[a * 32])[j];
        vv[j] = ((const float4*)&Vs[a * 32])[j];
      }
      ASTEP(qa, kk, vv, mA, zA, oA);
      if (vB) ASTEP(qb_, kk, vv, mB, zB, oB);
    }
  }

  {
    float zi = 1.0f / zA;
    ushort* dst = contentB + ((size_t)(b * MAXQ + qA)) * 256 + h * 32;
#pragma unroll
    for (int j = 0; j < 8; ++j) {
      ushort4 s;
      s.x = f2bf(oA[j].x * zi); s.y = f2bf(oA[j].y * zi);
      s.z = f2bf(oA[j].z * zi); s.w = f2bf(oA[j].w * zi);
      ((ushort4*)dst)[j] = s;
    }
  }
  if (vB) {
    float zi = 1.0f / zB;
    ushort* dst = contentB + ((size_t)(b * MAXQ + qB)) * 256 + h * 32;
#pragma unroll
    for (int j = 0; j < 8; ++j) {
      ushort4 s;
      s.x = f2bf(oB[j].x * zi); s.y = f2bf(oB[j].y * zi);
      s.z = f2bf(oB[j].z * zi); s.w = f2bf(oB[j].w * zi);
      ((ushort4*)dst)[j] = s;
    }
  }
}

// ---------------------------------------------------------------------------
extern "C" void kernel_launch(void* const* d_in, const int* in_sizes, int n_in,
                              void* d_out, int out_size, void* d_ws, size_t ws_size,
                              hipStream_t stream) {
  const float* density = (const float*)d_in[0];
  const float* pcount  = (const float*)d_in[1];
  const float* mem     = (const float*)d_in[2];
  const float* af      = (const float*)d_in[3];
  const float* pw1     = (const float*)d_in[4];
  const float* pb1     = (const float*)d_in[5];
  const float* pw2     = (const float*)d_in[6];
  const float* pb2     = (const float*)d_in[7];
  const float* inw     = (const float*)d_in[8];
  const float* inb     = (const float*)d_in[9];
  const float* outw    = (const float*)d_in[10];
  const float* outb    = (const float*)d_in[11];
  const float* qw      = (const float*)d_in[12];
  const float* qb      = (const float*)d_in[13];

  float* out = (float*)d_out;
  float* ws = (float*)d_ws;

  // ws layout (float offsets; all 16B-aligned)
  float*  positions = ws;                          // 25,600 (pad 32,768)
  float*  lgtab     = ws + 32768;                  // 102,400 (pad to 139,264)
  float*  Qbuf      = ws + 139264;                 // 3,276,800 f32
  float*  KV        = Qbuf + 3276800;              // 2,097,152 f32 [4096][512]
  ushort* sampledB  = (ushort*)(KV + 2097152);     // 3,276,800 bf16
  ushort* contentB  = sampledB + 3276800;          // 3,276,800 bf16
  ushort* agentB    = contentB + 3276800;          // 1,048,576 bf16 [4096][256]
  ushort* afB       = agentB + 1048576;            // 262,144 bf16 [4096][64]
  ushort* inwB      = afB + 262144;                // 196,608 bf16 [768][256]
  ushort* outwB     = inwB + 196608;               // 65,536 bf16
  ushort* qwtB      = outwB + 65536;               // 16,384 bf16 [256][64]
  int*    nq_i      = (int*)(qwtB + 16384);        // 16

  float* out_queries = out;                        // 3,276,800
  float* out_qpos    = out + 3276800;              // 3,276,800
  float* out_nq      = out + 6553600;              // 16
  float* out_mask    = out + 6553616;              // 12,800

  prep_kernel<<<(540672 + 255) / 256, 256, 0, stream>>>(
      pcount, nq_i, out_nq, density, lgtab, inw, outw, qw, af,
      inwB, outwB, qwtB, afB);
  sample_kernel<<<BQ, 256, 0, stream>>>(lgtab, nq_i, positions, out_mask);
  posmlp_kernel<<<BQ / 16, 256, 0, stream>>>(positions, pw1, pb1, pw2, pb2, out_qpos);
  bilinear_kernel<<<BQ, 64, 0, stream>>>(mem, positions, sampledB);
  // agent_init = af @ qw + qb  (bf16 out)
  mfma_gemm<1><<<dim3(4096 / 64, 4), 256, 0, stream>>>(
      afB, 64, qwtB, 64, qb, nullptr, agentB, 256);
  // Q = sampled @ Wq^T + bq  (f32 out)
  mfma_gemm<0><<<dim3(BQ / 64, 4), 256, 0, stream>>>(
      sampledB, 256, inwB, 256, inb, nullptr, Qbuf, 256);
  // K|V = agent @ [Wk;Wv]^T + [bk;bv]  (f32 out, [4096][512])
  mfma_gemm<0><<<dim3(4096 / 64, 8), 256, 0, stream>>>(
      agentB, 256, inwB + 256 * 256, 256, inb + 256, nullptr, KV, 512);
  // content (bf16 out)
  attn_kernel<<<dim3(4, 8, NB), 128, 0, stream>>>(Qbuf, KV, contentB);
  // queries = content @ out_w^T + out_b + query_pos  (f32 out)
  mfma_gemm<0><<<dim3(BQ / 64, 4), 256, 0, stream>>>(
      contentB, 256, outwB, 256, outb, out_qpos, out_queries, 256);
}

// Round 8
// 484.838 us; speedup vs baseline: 2.5592x; 1.3874x over previous
//
#include <hip/hip_runtime.h>
#include <stdint.h>
#include <math.h>

#define NB 16
#define HD_ 80
#define WD_ 80
#define HWD 6400
#define MAXQ 800
#define EMB 256
#define NMEM 8400
#define BQ (NB*MAXQ)          // 12800

typedef __attribute__((ext_vector_type(8))) short bf16x8;
typedef __attribute__((ext_vector_type(8))) unsigned short ushort8;
typedef __attribute__((ext_vector_type(4))) float f32x4;

__device__ __forceinline__ ushort f2bf(float f) {
  uint32_t u = __float_as_uint(f);
  uint32_t r = (u + 0x7FFFu + ((u >> 16) & 1u)) >> 16;
  return (ushort)r;
}

// ---------------------------------------------------------------------------
// Threefry2x32 key (0,42), partitionable: bits = o0^o1, x0 = hi32 = 0.
// Rotates forced to v_alignbit_b32 (rotl r == rotr (32-r)).
__device__ __forceinline__ void tf2x32(uint32_t x0, uint32_t x1,
                                       uint32_t& o0, uint32_t& o1) {
  const uint32_t ks0 = 0u;
  const uint32_t ks1 = 42u;
  const uint32_t ks2 = 0x1BD11BDAu ^ 0u ^ 42u;
  x0 += ks0; x1 += ks1;
#define TF_ROT(r) { x0 += x1; x1 = __builtin_amdgcn_alignbit(x1, x1, 32 - (r)); x1 ^= x0; }
  TF_ROT(13) TF_ROT(15) TF_ROT(26) TF_ROT(6)
  x0 += ks1; x1 += ks2 + 1u;
  TF_ROT(17) TF_ROT(29) TF_ROT(16) TF_ROT(24)
  x0 += ks2; x1 += ks0 + 2u;
  TF_ROT(13) TF_ROT(15) TF_ROT(26) TF_ROT(6)
  x0 += ks0; x1 += ks1 + 3u;
  TF_ROT(17) TF_ROT(29) TF_ROT(16) TF_ROT(24)
  x0 += ks1; x1 += ks2 + 4u;
  TF_ROT(13) TF_ROT(15) TF_ROT(26) TF_ROT(6)
  x0 += ks2; x1 += ks0 + 5u;
#undef TF_ROT
  o0 = x0; o1 = x1;
}

// ---------------------------------------------------------------------------
// prep: nq, lgtab = density/0.1 + C0 (C0 = -ln2*log2(ln2), folds the gumbel
// constant so sample's val = lgtab + NLN2*log2(-log2(u))), plus fp32->bf16
// conversions.
__global__ __launch_bounds__(256)
void prep_kernel(const float* __restrict__ pc, int* __restrict__ nq_i,
                 float* __restrict__ out_nq,
                 const float* __restrict__ density, float* __restrict__ lgtab,
                 const float* __restrict__ inw, const float* __restrict__ outw,
                 const float* __restrict__ qw, const float* __restrict__ af,
                 ushort* __restrict__ inwB, ushort* __restrict__ outwB,
                 ushort* __restrict__ qwtB, ushort* __restrict__ afB) {
  int i = blockIdx.x * 256 + threadIdx.x;
  if (i < NB * HWD) lgtab[i] = density[i] / 0.1f + 0.36651292058166432701f;
  if (i < NB) {
    float v = floorf(pc[i] * 2.0f);
    int n = (int)v;
    n = n < 100 ? 100 : (n > 800 ? 800 : n);
    nq_i[i] = n;
    out_nq[i] = (float)n;
  }
  if (i < 196608) {
    inwB[i] = f2bf(inw[i]);
  } else if (i < 196608 + 65536) {
    int j = i - 196608;
    outwB[j] = f2bf(outw[j]);
  } else if (i < 196608 + 65536 + 16384) {
    int j = i - (196608 + 65536);
    int c = j >> 6, k = j & 63;           // qwtB[c][k] = qw[k][c]
    qwtB[j] = f2bf(qw[k * 256 + c]);
  } else if (i < 196608 + 65536 + 16384 + 262144) {
    int j = i - (196608 + 65536 + 16384);
    afB[j] = f2bf(af[j]);
  }
}

// ---------------------------------------------------------------------------
// Gumbel-max categorical sampling. val = lgtab + NLN2*log2(-log2(u));
// u==0 -> log2(u)=-inf -> log2(+inf)=+inf -> val=-inf (never selected).
__global__ __launch_bounds__(256)
void sample_kernel(const float* __restrict__ lgs, const int* __restrict__ nq_i,
                   float* __restrict__ positions, float* __restrict__ mask_out) {
  __shared__ float swv[4];
  __shared__ int   swi[4];
  const int bq = blockIdx.x;
  const int b = bq / MAXQ;
  const int q = bq - b * MAXQ;
  const int t = threadIdx.x;
  const float* lg = lgs + b * HWD;
  const uint32_t base = (uint32_t)bq * (uint32_t)HWD;  // < 2^32

  const float NLN2 = -0.69314718055994530942f;
  float best = -3.0e38f;
  int besti = HWD;
#pragma unroll 5
  for (int i = 0; i < 25; ++i) {
    int c = t + (i << 8);
    uint32_t o0, o1;
    tf2x32(0u, base + (uint32_t)c, o0, o1);
    uint32_t bits = o0 ^ o1;
    float u = __uint_as_float((bits >> 9) | 0x3f800000u) - 1.0f;
    float l2;
    asm("v_log_f32 %0, %1" : "=v"(l2) : "v"(u));    // log2(u) <= 0
    float l4;
    asm("v_log_f32 %0, -%1" : "=v"(l4) : "v"(l2));  // log2(-log2(u))
    float val = fmaf(NLN2, l4, lg[c]);
    if (val > best) { best = val; besti = c; }      // per-thread c ascending
  }
#pragma unroll
  for (int off = 32; off; off >>= 1) {
    float ov = __shfl_xor(best, off);
    int   oi = __shfl_xor(besti, off);
    if (ov > best || (ov == best && oi < besti)) { best = ov; besti = oi; }
  }
  if ((t & 63) == 0) { swv[t >> 6] = best; swi[t >> 6] = besti; }
  __syncthreads();
  if (t == 0) {
    float bv = swv[0]; int bi = swi[0];
#pragma unroll
    for (int w = 1; w < 4; ++w) {
      float ov = swv[w]; int oi = swi[w];
      if (ov > bv || (ov == bv && oi < bi)) { bv = ov; bi = oi; }
    }
    int n = nq_i[b];
    float px, py;
    if (q >= n) { px = 0.0f; py = 0.0f; }
    else {
      py = (float)(bi / WD_) / 80.0f;
      px = (float)(bi % WD_) / 80.0f;
    }
    positions[2 * bq]     = px;
    positions[2 * bq + 1] = py;
    mask_out[bq] = (q >= n) ? 1.0f : 0.0f;
  }
}

// ---------------------------------------------------------------------------
__device__ __forceinline__ float gelu_tanh(float x) {
  float x3 = x * x * x;
  float inner = 0.7978845608028654f * (x + 0.044715f * x3);
  float cdf = 0.5f * (1.0f + tanhf(inner));
  return x * cdf;
}

__global__ __launch_bounds__(256)
void posmlp_kernel(const float* __restrict__ positions,
                   const float* __restrict__ w1, const float* __restrict__ b1,
                   const float* __restrict__ w2, const float* __restrict__ b2,
                   float* __restrict__ qpos) {
  __shared__ float ppos[16][2];
  __shared__ float h_all[16 * 128];
  const int t = threadIdx.x;
  const size_t q0 = (size_t)blockIdx.x * 16;
  if (t < 32) ppos[t >> 1][t & 1] = positions[q0 * 2 + t];
  __syncthreads();
  for (int j = t; j < 2048; j += 256) {
    int qi = j >> 7, k = j & 127;
    float x = ppos[qi][0] * w1[k] + ppos[qi][1] * w1[128 + k] + b1[k];
    h_all[j] = gelu_tanh(x);
  }
  __syncthreads();
  float acc[16];
#pragma unroll
  for (int qi = 0; qi < 16; ++qi) acc[qi] = 0.0f;
  for (int k4 = 0; k4 < 32; ++k4) {
    float wv0 = w2[(k4 * 4 + 0) * 256 + t];
    float wv1 = w2[(k4 * 4 + 1) * 256 + t];
    float wv2 = w2[(k4 * 4 + 2) * 256 + t];
    float wv3 = w2[(k4 * 4 + 3) * 256 + t];
#pragma unroll
    for (int qi = 0; qi < 16; ++qi) {
      float4 h4 = *(const float4*)&h_all[qi * 128 + k4 * 4];
      acc[qi] = fmaf(h4.x, wv0, fmaf(h4.y, wv1, fmaf(h4.z, wv2, fmaf(h4.w, wv3, acc[qi]))));
    }
  }
  float bv = b2[t];
#pragma unroll
  for (int qi = 0; qi < 16; ++qi)
    qpos[(q0 + qi) * 256 + t] = acc[qi] + bv;
}

// ---------------------------------------------------------------------------
__global__ __launch_bounds__(64)
void bilinear_kernel(const float* __restrict__ mem,
                     const float* __restrict__ positions,
                     ushort* __restrict__ sampledB) {
  const int bq = blockIdx.x;
  const int b = bq / MAXQ;
  const int t = threadIdx.x;
  float px = positions[2 * bq], py = positions[2 * bq + 1];
  float gx = px * 2.0f - 1.0f;
  float gy = py * 2.0f - 1.0f;
  float x = (gx + 1.0f) * 0.5f * 80.0f - 0.5f;
  float y = (gy + 1.0f) * 0.5f * 80.0f - 0.5f;
  float x0f = floorf(x), y0f = floorf(y);
  float wx1 = x - x0f, wx0 = 1.0f - wx1;
  float wy1 = y - y0f, wy0 = 1.0f - wy1;
  int x0 = (int)x0f, y0 = (int)y0f;
  int x1 = x0 + 1, y1 = y0 + 1;
  const float4* fmb = (const float4*)(mem + (size_t)b * NMEM * EMB);
  float4 acc = make_float4(0.f, 0.f, 0.f, 0.f);
#define BIL_CORNER(yy, xx, wt) \
  if ((yy) >= 0 && (yy) < HD_ && (xx) >= 0 && (xx) < WD_) {            \
    float4 v = fmb[(size_t)((yy) * WD_ + (xx)) * 64 + t];              \
    acc.x += (wt) * v.x; acc.y += (wt) * v.y;                          \
    acc.z += (wt) * v.z; acc.w += (wt) * v.w; }
  BIL_CORNER(y0, x0, wy0 * wx0)
  BIL_CORNER(y0, x1, wy0 * wx1)
  BIL_CORNER(y1, x0, wy1 * wx0)
  BIL_CORNER(y1, x1, wy1 * wx1)
#undef BIL_CORNER
  ushort4 s;
  s.x = f2bf(acc.x); s.y = f2bf(acc.y); s.z = f2bf(acc.z); s.w = f2bf(acc.w);
  ((ushort4*)sampledB)[(size_t)bq * 64 + t] = s;
}

// ---------------------------------------------------------------------------
// MFMA bf16 GEMM (as round 7, verified): out[r][c] = X[r][:]·W[c][:] + bias
// (+ add). Tile 64x64, 4 waves, 16x16x32.
template<int OUTBF16>
__global__ __launch_bounds__(256)
void mfma_gemm(const ushort* __restrict__ X, int ldx,
               const ushort* __restrict__ W, int K,
               const float* __restrict__ bias, const float* __restrict__ add,
               void* __restrict__ out, int ldc) {
  __shared__ ushort Xs[64 * 32];
  __shared__ ushort Ws[64 * 32];
  const int t = threadIdx.x;
  const size_t row0 = (size_t)blockIdx.x * 64;
  const int col0 = blockIdx.y * 64;
  const int w = t >> 6, lane = t & 63;
  const int wm = w >> 1, wn = w & 1;
  const int lr = lane & 15, lg = lane >> 4;
  const int swl = (lg ^ (lr & 3)) * 8;
  const int srow = t >> 2, sg = t & 3;
  const int sdst = srow * 32 + ((sg ^ (srow & 3)) * 8);

  f32x4 acc[2][2];
#pragma unroll
  for (int mi = 0; mi < 2; ++mi)
#pragma unroll
    for (int ni = 0; ni < 2; ++ni) acc[mi][ni] = 0.0f;

  const int nk = K >> 5;
  for (int kt = 0; kt < nk; ++kt) {
    const int k0 = kt * 32;
    uint4 xv = *(const uint4*)(X + (row0 + srow) * ldx + k0 + sg * 8);
    uint4 wv = *(const uint4*)(W + (size_t)(col0 + srow) * K + k0 + sg * 8);
    *(uint4*)&Xs[sdst] = xv;
    *(uint4*)&Ws[sdst] = wv;
    __syncthreads();
    bf16x8 a[2], b[2];
#pragma unroll
    for (int mi = 0; mi < 2; ++mi)
      a[mi] = *(const bf16x8*)&Xs[(wm * 32 + mi * 16 + lr) * 32 + swl];
#pragma unroll
    for (int ni = 0; ni < 2; ++ni)
      b[ni] = *(const bf16x8*)&Ws[(wn * 32 + ni * 16 + lr) * 32 + swl];
#pragma unroll
    for (int mi = 0; mi < 2; ++mi)
#pragma unroll
      for (int ni = 0; ni < 2; ++ni)
        acc[mi][ni] = __builtin_amdgcn_mfma_f32_16x16x32_bf16(a[mi], b[ni], acc[mi][ni], 0, 0, 0);
    __syncthreads();
  }

#pragma unroll
  for (int mi = 0; mi < 2; ++mi)
#pragma unroll
    for (int ni = 0; ni < 2; ++ni) {
      const int gcol = col0 + wn * 32 + ni * 16 + lr;
      const float bv = bias[gcol];
#pragma unroll
      for (int rr = 0; rr < 4; ++rr) {
        const size_t grow = row0 + wm * 32 + mi * 16 + lg * 4 + rr;
        float v = acc[mi][ni][rr] + bv;
        if (add) v += add[grow * ldc + gcol];
        if (OUTBF16) ((ushort*)out)[grow * ldc + gcol] = f2bf(v);
        else         ((float*)out)[grow * ldc + gcol] = v;
      }
    }
}

// ---------------------------------------------------------------------------
// MFMA flash attention. Block = (qtile 64, head, batch), 256 thr (4 waves,
// wave -> 16 queries). Q/K frags read direct from global (L2-hot). S[16][256]
// = 16 MFMAs. Full-row softmax in registers (16-lane shfl groups). P stored
// bf16 in LDS with alpha-permutation alpha(a) = (a&15)*16 + (a>>4) (lane's 16
// agents contiguous -> cvt_pk + b128 writes); V^T staged with the SAME
// permutation, so PV contraction is consistent. XOR swizzle ^((row&7)<<4 B)
// on both kills the 512B-stride bank conflict. Norm deferred to O.
__global__ __launch_bounds__(256)
void attn_kernel(const ushort* __restrict__ Qb, const ushort* __restrict__ KVb,
                 ushort* __restrict__ contentB) {
  __shared__ __align__(16) ushort Vt[32 * 256];   // [d][alpha]
  __shared__ __align__(16) ushort Ps[64 * 256];   // [q][alpha]
  const int t = threadIdx.x;
  const int qt = blockIdx.x, h = blockIdx.y, b = blockIdx.z;
  const int q0 = qt * 64;
  const int w = t >> 6, lane = t & 63;
  const int lr = lane & 15, lg = lane >> 4;
  const ushort* KVrow = KVb + (size_t)b * 256 * 512;

  // ---- stage V^T (alpha-permuted, swizzled) ----
#pragma unroll
  for (int i = 0; i < 4; ++i) {
    int task = t + 256 * i;
    int a = task & 255, dblk = task >> 8;
    ushort8 v = *(const ushort8*)(KVrow + (size_t)a * 512 + 256 + h * 32 + dblk * 8);
    int alpha = ((a & 15) << 4) | (a >> 4);
#pragma unroll
    for (int j = 0; j < 8; ++j) {
      int d = dblk * 8 + j;
      Vt[(d * 256 + alpha) ^ ((d & 7) << 3)] = v[j];
    }
  }

  // ---- scores: S[16 q][256 a] per wave ----
  int qrow = q0 + w * 16 + lr; if (qrow > MAXQ - 1) qrow = MAXQ - 1;
  bf16x8 aq = *(const bf16x8*)(Qb + ((size_t)b * MAXQ + qrow) * 256 + h * 32 + lg * 8);
  f32x4 zero = {0.f, 0.f, 0.f, 0.f};
  f32x4 accs[16];
#pragma unroll
  for (int ni = 0; ni < 16; ++ni) {
    bf16x8 bk = *(const bf16x8*)(KVrow + (size_t)(ni * 16 + lr) * 512 + h * 32 + lg * 8);
    accs[ni] = __builtin_amdgcn_mfma_f32_16x16x32_bf16(aq, bk, zero, 0, 0, 0);
  }
  const float SCALE = 0.17677669529663689f;   // 1/sqrt(32)
#pragma unroll
  for (int ni = 0; ni < 16; ++ni)
#pragma unroll
    for (int rr = 0; rr < 4; ++rr) accs[ni][rr] *= SCALE;

  // ---- softmax rows q = w*16 + 4*lg + rr ----
  float rsum[4];
#pragma unroll
  for (int rr = 0; rr < 4; ++rr) {
    float m = accs[0][rr];
#pragma unroll
    for (int ni = 1; ni < 16; ++ni) m = fmaxf(m, accs[ni][rr]);
#pragma unroll
    for (int off = 1; off < 16; off <<= 1) m = fmaxf(m, __shfl_xor(m, off));
#pragma unroll
    for (int ni = 0; ni < 16; ++ni) accs[ni][rr] = __expf(accs[ni][rr] - m);
    float z = accs[0][rr];
#pragma unroll
    for (int ni = 1; ni < 16; ++ni) z += accs[ni][rr];
#pragma unroll
    for (int off = 1; off < 16; off <<= 1) z += __shfl_xor(z, off);
    rsum[rr] = z;
  }

  // ---- write P (unnormalized) to LDS: q row, alpha = lr*16 + ni ----
#pragma unroll
  for (int rr = 0; rr < 4; ++rr) {
    int q = w * 16 + lg * 4 + rr;
    uint32_t pk[8];
#pragma unroll
    for (int k = 0; k < 8; ++k)
      asm("v_cvt_pk_bf16_f32 %0, %1, %2"
          : "=v"(pk[k]) : "v"(accs[2 * k][rr]), "v"(accs[2 * k + 1][rr]));
    uint4 u0; u0.x = pk[0]; u0.y = pk[1]; u0.z = pk[2]; u0.w = pk[3];
    uint4 u1; u1.x = pk[4]; u1.y = pk[5]; u1.z = pk[6]; u1.w = pk[7];
    *(uint4*)&Ps[(q * 256 + lr * 16) ^ ((q & 7) << 3)] = u0;
    *(uint4*)&Ps[(q * 256 + lr * 16 + 8) ^ ((q & 7) << 3)] = u1;
  }

  __syncthreads();

  // ---- PV: O[16 q][32 d] per wave ----
  f32x4 acco[2] = {zero, zero};
  const int qr = w * 16 + lr;
#pragma unroll
  for (int ks = 0; ks < 8; ++ks) {
    bf16x8 ap = *(const bf16x8*)&Ps[(qr * 256 + ks * 32 + lg * 8) ^ ((qr & 7) << 3)];
#pragma unroll
    for (int ni = 0; ni < 2; ++ni) {
      int d = ni * 16 + lr;
      bf16x8 bv = *(const bf16x8*)&Vt[(d * 256 + ks * 32 + lg * 8) ^ ((d & 7) << 3)];
      acco[ni] = __builtin_amdgcn_mfma_f32_16x16x32_bf16(ap, bv, acco[ni], 0, 0, 0);
    }
  }

  // ---- store O (normalize by rsum; rows match D layout) ----
#pragma unroll
  for (int rr = 0; rr < 4; ++rr) {
    int q = q0 + w * 16 + lg * 4 + rr;
    if (q < MAXQ) {
      float zi = 1.0f / rsum[rr];
#pragma unroll
      for (int ni = 0; ni < 2; ++ni) {
        int d = ni * 16 + lr;
        contentB[((size_t)b * MAXQ + q) * 256 + h * 32 + d] = f2bf(acco[ni][rr] * zi);
      }
    }
  }
}

// ---------------------------------------------------------------------------
extern "C" void kernel_launch(void* const* d_in, const int* in_sizes, int n_in,
                              void* d_out, int out_size, void* d_ws, size_t ws_size,
                              hipStream_t stream) {
  const float* density = (const float*)d_in[0];
  const float* pcount  = (const float*)d_in[1];
  const float* mem     = (const float*)d_in[2];
  const float* af      = (const float*)d_in[3];
  const float* pw1     = (const float*)d_in[4];
  const float* pb1     = (const float*)d_in[5];
  const float* pw2     = (const float*)d_in[6];
  const float* pb2     = (const float*)d_in[7];
  const float* inw     = (const float*)d_in[8];
  const float* inb     = (const float*)d_in[9];
  const float* outw    = (const float*)d_in[10];
  const float* outb    = (const float*)d_in[11];
  const float* qw      = (const float*)d_in[12];
  const float* qb      = (const float*)d_in[13];

  float* out = (float*)d_out;
  float* ws = (float*)d_ws;

  // ws layout (float offsets; 16B aligned)
  float*  positions = ws;                          // 25,600 (pad 32,768)
  float*  lgtab     = ws + 32768;                  // 102,400 (pad to 139,264)
  ushort* Qb        = (ushort*)(ws + 139264);      // 3,276,800 bf16 [12800][256]
  ushort* KVb       = Qb + 3276800;                // 2,097,152 bf16 [4096][512]
  ushort* sampledB  = KVb + 2097152;               // 3,276,800 bf16
  ushort* contentB  = sampledB + 3276800;          // 3,276,800 bf16
  ushort* agentB    = contentB + 3276800;          // 1,048,576 bf16 [4096][256]
  ushort* afB       = agentB + 1048576;            // 262,144 bf16 [4096][64]
  ushort* inwB      = afB + 262144;                // 196,608 bf16 [768][256]
  ushort* outwB     = inwB + 196608;               // 65,536 bf16
  ushort* qwtB      = outwB + 65536;               // 16,384 bf16 [256][64]
  int*    nq_i      = (int*)(qwtB + 16384);        // 16

  float* out_queries = out;                        // 3,276,800
  float* out_qpos    = out + 3276800;              // 3,276,800
  float* out_nq      = out + 6553600;              // 16
  float* out_mask    = out + 6553616;              // 12,800

  prep_kernel<<<(540672 + 255) / 256, 256, 0, stream>>>(
      pcount, nq_i, out_nq, density, lgtab, inw, outw, qw, af,
      inwB, outwB, qwtB, afB);
  sample_kernel<<<BQ, 256, 0, stream>>>(lgtab, nq_i, positions, out_mask);
  posmlp_kernel<<<BQ / 16, 256, 0, stream>>>(positions, pw1, pb1, pw2, pb2, out_qpos);
  bilinear_kernel<<<BQ, 64, 0, stream>>>(mem, positions, sampledB);
  // agent_init = af @ qw + qb  (bf16)
  mfma_gemm<1><<<dim3(4096 / 64, 4), 256, 0, stream>>>(
      afB, 64, qwtB, 64, qb, nullptr, agentB, 256);
  // Q = sampled @ Wq^T + bq  (bf16)
  mfma_gemm<1><<<dim3(BQ / 64, 4), 256, 0, stream>>>(
      sampledB, 256, inwB, 256, inb, nullptr, Qb, 256);
  // K|V = agent @ [Wk;Wv]^T + [bk;bv]  (bf16, [4096][512])
  mfma_gemm<1><<<dim3(4096 / 64, 8), 256, 0, stream>>>(
      agentB, 256, inwB + 256 * 256, 256, inb + 256, nullptr, KVb, 512);
  // content (bf16)
  attn_kernel<<<dim3(13, 8, NB), 256, 0, stream>>>(Qb, KVb, contentB);
  // queries = content @ out_w^T + out_b + query_pos  (f32)
  mfma_gemm<0><<<dim3(BQ / 64, 4), 256, 0, stream>>>(
      contentB, 256, outwB, 256, outb, out_qpos, out_queries, 256);
}